// Round 1
// baseline (436.254 us; speedup 1.0000x reference)
//
#include <hip/hip_runtime.h>
#include <stdint.h>

typedef __attribute__((ext_vector_type(4))) float floatx4;
typedef __attribute__((ext_vector_type(16))) float floatx16;
typedef __attribute__((ext_vector_type(8))) short short8;

// Problem constants
#define BB 16
#define SS 512
#define DD 2048
#define HH_ 16
#define HD 128
#define GG 4
#define MM (BB*SS)          // 8192
#define NQKV 3072           // 2048 q + 512 k + 512 v

__device__ __forceinline__ unsigned short f2bf(float f){
  unsigned u = __builtin_bit_cast(unsigned, f);
  u += 0x7fffu + ((u >> 16) & 1u);            // RNE
  return (unsigned short)(u >> 16);
}
__device__ __forceinline__ float bf2f_lo(unsigned d){
  return __builtin_bit_cast(float, d << 16);
}
__device__ __forceinline__ float bf2f_hi(unsigned d){
  return __builtin_bit_cast(float, d & 0xffff0000u);
}

// NOTE: LDS dest must be WAVE-UNIFORM; HW writes base + lane*16.
__device__ __forceinline__ void async_copy16(const void* g, void* l){
  __builtin_amdgcn_global_load_lds((const __attribute__((address_space(1))) unsigned*)g,
                                   (__attribute__((address_space(3))) unsigned*)l,
                                   16, 0, 0);
}

// ---------------- fused prep: cvt_x | 4x transpose | bias concat ----------------
#define PB_CVT   16384
#define PB_TRQ   (PB_CVT + 4096)
#define PB_TRK   (PB_TRQ + 1024)
#define PB_TRV   (PB_TRK + 1024)
#define PB_TRO   (PB_TRV + 4096)
#define PB_ALL   (PB_TRO + 12)

__global__ __launch_bounds__(256) void prep_kernel(
    const float* __restrict__ x,
    const float* __restrict__ Wq, const float* __restrict__ Wk,
    const float* __restrict__ Wv, const float* __restrict__ Wo,
    const float* __restrict__ bq, const float* __restrict__ bk,
    const float* __restrict__ bv,
    unsigned short* __restrict__ xb, unsigned short* __restrict__ WqkvT,
    unsigned short* __restrict__ WoT, float* __restrict__ bqkv)
{
  __shared__ float tile[32][33];
  const int bid = blockIdx.x, tid = threadIdx.x;

  if (bid < PB_CVT) {                       // ---- x fp32 -> bf16 ----
    const int i = bid * 256 + tid;
    float4 f = ((const float4*)x)[i];
    ushort4 o;
    o.x = f2bf(f.x); o.y = f2bf(f.y); o.z = f2bf(f.z); o.w = f2bf(f.w);
    ((ushort4*)xb)[i] = o;
    return;
  }
  if (bid < PB_TRO) {                       // ---- W transpose+cvt ----
    const float* src; unsigned short* dst; int R, C, b2;
    if (bid < PB_TRQ)      { src = Wq; dst = WqkvT;                          R = 2048; C = 2048; b2 = bid - PB_CVT; }
    else if (bid < PB_TRK) { src = Wk; dst = WqkvT + (size_t)2048 * 2048;    R = 2048; C = 512;  b2 = bid - PB_TRQ; }
    else if (bid < PB_TRV) { src = Wv; dst = WqkvT + (size_t)2560 * 2048;    R = 2048; C = 512;  b2 = bid - PB_TRK; }
    else                   { src = Wo; dst = WoT;                            R = 2048; C = 2048; b2 = bid - PB_TRV; }
    const int nbx = C >> 5;
    const int c0 = (b2 % nbx) * 32, r0 = (b2 / nbx) * 32;
    const int tx = tid & 31, ty = tid >> 5;          // 32 x 8
    #pragma unroll
    for (int j = 0; j < 32; j += 8)
      tile[ty + j][tx] = src[(size_t)(r0 + ty + j) * C + (c0 + tx)];
    __syncthreads();
    #pragma unroll
    for (int j = 0; j < 32; j += 8)
      dst[(size_t)(c0 + ty + j) * R + (r0 + tx)] = f2bf(tile[tx][ty + j]);
    return;
  }
  {                                         // ---- bias concat ----
    const int i = (bid - PB_TRO) * 256 + tid;
    if (i < NQKV)
      bqkv[i] = (i < 2048) ? bq[i] : (i < 2560 ? bk[i - 2048] : bv[i - 2560]);
  }
}

// ---------------- 256x256 8-phase bf16 GEMM: C = A(MxK) @ Bt(NxK)^T + bias ----
// Port of the m201/HK 8-phase schedule to this problem. 8 waves (2Mx4N),
// wave tile 128x64, BK=64, 16x16x32 MFMA, acc[8][4] = 128 VGPR.
// LDS: 4 half-slots per operand (ring at half-tile granularity), 128 KiB.
// Granule-XOR swizzle: logical granule g of row r stored at slot g^(r&7);
// applied by pre-swizzling the GLOBAL source (global_load_lds dest is
// wave-uniform, HW adds lane*16B), and un-applied on ds_read.
//
// Per K-tile t (4 phases, 2 barriers each, raw s_barrier — no drain):
//  P0: ds_read A-lo(8)+B-lo(4) | stage A1(t+1) | MFMA Alo x B0 (16)
//  P1: ds_read B-hi(4)         | stage B0(t+2) | MFMA Alo x B1 (16)
//  P2: ds_read A-hi(8)         | stage B1(t+2) | MFMA Ahi x B0 (16)
//  P3:                         | stage A0(t+2) + vmcnt(6) | MFMA Ahi x B1
// vmcnt(6): exactly the 3 most recent half-tiles (B0,B1,A0 of t+2) may stay
// in flight; everything older (incl. all of tile t+1) has landed.
// Slot-liveness verified: every stage targets the slot of a half whose last
// ds_read completed >=1 barrier before the stage issue.
template<bool OUT_BF16>
__global__ __launch_bounds__(512, 2) void gemm256_kernel(
    const unsigned short* __restrict__ A,
    const unsigned short* __restrict__ Bt,
    void* __restrict__ Cout,
    const float* __restrict__ bias,
    int N, int K, int ldc)
{
  __shared__ unsigned short sA[4 * 128 * 64];   // 64 KB: 4 half-slots
  __shared__ unsigned short sB[4 * 128 * 64];   // 64 KB

  const int tid  = threadIdx.x;
  const int wave = tid >> 6, lane = tid & 63;
  const int wm = wave >> 2, wn = wave & 3;      // 2 x 4 wave grid
  const int l15 = lane & 15, l7 = lane & 7, q4 = lane >> 4;

  // bijective XCD swizzle (grid % 8 == 0 for both call sites)
  const int nbn = N >> 8;
  const int cpx = gridDim.x >> 3;
  const int bid = (blockIdx.x & 7) * cpx + (blockIdx.x >> 3);
  const int m0 = (bid / nbn) * 256;
  const int n0 = (bid % nbn) * 256;

  // staging: round covers 64 rows; lane l -> row wave*8+(l>>3), slot l&7,
  // fetches logical granule (l&7)^(row&7)
  const int rowOff = wave * 8 + (lane >> 3);
  const int glog   = l7 ^ ((lane >> 3) & 7);
  const unsigned short* gA = A  + (size_t)(m0 + rowOff) * K + glog * 8;
  const unsigned short* gB = Bt + (size_t)(n0 + rowOff) * K + glog * 8;

#define STAGE_A(j, tt) do { \
    unsigned short* d_ = &sA[(2 * ((tt) & 1) + (j)) * 8192 + wave * 512]; \
    const unsigned short* s_ = gA + (size_t)((j) * 128) * K + (tt) * 64; \
    async_copy16(s_, d_); \
    async_copy16(s_ + (size_t)64 * K, d_ + 4096); } while (0)
#define STAGE_B(j, tt) do { \
    unsigned short* d_ = &sB[(2 * ((tt) & 1) + (j)) * 8192 + wave * 512]; \
    const unsigned short* s_ = gB + (size_t)((j) * 128) * K + (tt) * 64; \
    async_copy16(s_, d_); \
    async_copy16(s_ + (size_t)64 * K, d_ + 4096); } while (0)

  // prologue: B0(0) B1(0) A0(0) A1(0) B0(1) B1(1) A0(1) -> 14 loads;
  // vmcnt(6) retires the oldest 8 = all of tile 0.
  STAGE_B(0, 0); STAGE_B(1, 0); STAGE_A(0, 0); STAGE_A(1, 0);
  STAGE_B(0, 1); STAGE_B(1, 1); STAGE_A(0, 1);

  floatx4 acc[8][4];
  #pragma unroll
  for (int i = 0; i < 8; ++i)
    #pragma unroll
    for (int j = 0; j < 4; ++j)
      acc[i][j] = (floatx4){0.f, 0.f, 0.f, 0.f};

  asm volatile("s_waitcnt vmcnt(6)" ::: "memory");
  __builtin_amdgcn_s_barrier();

  short8 aF[4][2], bF[4][2];
  const int NT = K >> 6;

  // per-thread LDS read bases; frag: row = base + f*16 + l15,
  // k-chunk kk granule = kk*4 + q4, phys slot = granule ^ (row&7) = ^l7
  const unsigned short* pA = &sA[l15 * 64];
  const unsigned short* pB = &sB[((wn & 1) * 64 + l15) * 64];
  const int g0 = ((0 + q4) ^ l7) * 8;
  const int g1 = ((4 + q4) ^ l7) * 8;

#define LDA_(fa_, rb_, sa_) do { \
    aF[fa_][0] = *(const short8*)(pA + (sa_) * 8192 + ((rb_) + (fa_) * 16) * 64 + g0); \
    aF[fa_][1] = *(const short8*)(pA + (sa_) * 8192 + ((rb_) + (fa_) * 16) * 64 + g1); } while (0)
#define LDB_(fb_, sb_) do { \
    bF[fb_][0] = *(const short8*)(pB + (sb_) * 8192 + (fb_) * 16 * 64 + g0); \
    bF[fb_][1] = *(const short8*)(pB + (sb_) * 8192 + (fb_) * 16 * 64 + g1); } while (0)
#define MFMA_Q(fa0, fb0) \
    _Pragma("unroll") \
    for (int fa = 0; fa < 4; ++fa) { \
      _Pragma("unroll") \
      for (int fb = 0; fb < 2; ++fb) { \
        acc[(fa0)+fa][(fb0)+fb] = __builtin_amdgcn_mfma_f32_16x16x32_bf16(aF[fa][0], bF[(fb0)+fb][0], acc[(fa0)+fa][(fb0)+fb], 0, 0, 0); \
        acc[(fa0)+fa][(fb0)+fb] = __builtin_amdgcn_mfma_f32_16x16x32_bf16(aF[fa][1], bF[(fb0)+fb][1], acc[(fa0)+fa][(fb0)+fb], 0, 0, 0); \
      } \
    }

  #pragma unroll 1
  for (int t = 0; t < NT; ++t) {
    const int sa = 2 * (t & 1) + wm;        // this wave's A half-slot
    const int sb = 2 * (t & 1) + (wn >> 1); // this wave's B half-slot
    // ---- P0 ----
    LDA_(0, 0, sa); LDA_(1, 0, sa); LDA_(2, 0, sa); LDA_(3, 0, sa);
    LDB_(0, sb); LDB_(1, sb);
    if (t + 1 < NT) STAGE_A(1, t + 1);
    __builtin_amdgcn_s_barrier();
    asm volatile("s_waitcnt lgkmcnt(0)" ::: "memory");
    __builtin_amdgcn_sched_barrier(0);
    __builtin_amdgcn_s_setprio(1);
    MFMA_Q(0, 0);
    __builtin_amdgcn_s_setprio(0);
    __builtin_amdgcn_s_barrier();
    // ---- P1 ----
    LDB_(2, sb); LDB_(3, sb);
    if (t + 2 < NT) STAGE_B(0, t + 2);
    __builtin_amdgcn_s_barrier();
    asm volatile("s_waitcnt lgkmcnt(0)" ::: "memory");
    __builtin_amdgcn_sched_barrier(0);
    __builtin_amdgcn_s_setprio(1);
    MFMA_Q(0, 2);
    __builtin_amdgcn_s_setprio(0);
    __builtin_amdgcn_s_barrier();
    // ---- P2 ----
    LDA_(0, 64, sa); LDA_(1, 64, sa); LDA_(2, 64, sa); LDA_(3, 64, sa);
    if (t + 2 < NT) STAGE_B(1, t + 2);
    __builtin_amdgcn_s_barrier();
    asm volatile("s_waitcnt lgkmcnt(0)" ::: "memory");
    __builtin_amdgcn_sched_barrier(0);
    __builtin_amdgcn_s_setprio(1);
    MFMA_Q(4, 0);
    __builtin_amdgcn_s_setprio(0);
    __builtin_amdgcn_s_barrier();
    // ---- P3 ----
    if (t + 2 < NT) {
      STAGE_A(0, t + 2);
      asm volatile("s_waitcnt vmcnt(6)" ::: "memory");
    } else if (t + 1 < NT) {
      asm volatile("s_waitcnt vmcnt(0)" ::: "memory");  // tail drain
    }
    __builtin_amdgcn_s_barrier();
    __builtin_amdgcn_s_setprio(1);
    MFMA_Q(4, 2);
    __builtin_amdgcn_s_setprio(0);
    __builtin_amdgcn_s_barrier();
  }
#undef STAGE_A
#undef STAGE_B
#undef LDA_
#undef LDB_
#undef MFMA_Q

  // epilogue: 16x16 C/D layout: col(N) = l15 (B index), row(M) = q4*4+reg (A)
  const int r4 = q4 * 4;
  #pragma unroll
  for (int fb = 0; fb < 4; ++fb) {
    const int col = n0 + wn * 64 + fb * 16 + l15;
    const float bval = bias[col];
    #pragma unroll
    for (int fa = 0; fa < 8; ++fa) {
      const size_t rowb = (size_t)(m0 + wm * 128 + fa * 16 + r4);
      #pragma unroll
      for (int r = 0; r < 4; ++r) {
        const float v = acc[fa][fb][r] + bval;
        if (OUT_BF16)
          ((unsigned short*)Cout)[(rowb + r) * ldc + col] = f2bf(v);
        else
          ((float*)Cout)[(rowb + r) * ldc + col] = v;
      }
    }
  }
}

// ---------------- fused RMSNorm+RoPE (q,k) | V transpose ----------------
__global__ __launch_bounds__(256) void norm_vtr_kernel(
    unsigned short* __restrict__ qkv,
    const float* __restrict__ qs, const float* __restrict__ ks,
    unsigned short* __restrict__ vt)
{
  __shared__ unsigned short tileV[32][34];
  const int bid = blockIdx.x, tid = threadIdx.x;

  if (bid < 40960) {
    const int wave = tid >> 6, lane = tid & 63;
    const int gw  = bid * 4 + wave;
    const int row = gw / 20;
    const int hh  = gw % 20;          // 0..15 q heads, 16..19 k heads
    const bool isq = hh < 16;

    unsigned* p = (unsigned*)(qkv + (size_t)row * NQKV + hh * 128) + lane;
    unsigned d = *p;
    float x1 = bf2f_lo(d), x2 = bf2f_hi(d);

    float ss = x1 * x1 + x2 * x2;
    #pragma unroll
    for (int off = 32; off; off >>= 1) ss += __shfl_xor(ss, off, 64);
    const float r = rsqrtf(ss * (1.f / 128.f) + 1e-6f);

    const float2 sc = ((const float2*)(isq ? qs : ks))[lane];
    float n1 = x1 * r * sc.x;
    float n2 = x2 * r * sc.y;

    const float t = (float)(row & (SS - 1));
    const float freq = __expf((float)lane * (-2.f / 128.f) * 9.21034037197618f);
    float sn, cs;
    __sincosf(t * freq, &sn, &cs);
    float o1 = n1 * cs - n2 * sn;
    float o2 = n1 * sn + n2 * cs;
    if (isq) { o1 *= (1.f / 128.f); o2 *= (1.f / 128.f); }

    *p = (unsigned)f2bf(o1) | ((unsigned)f2bf(o2) << 16);
    return;
  }
  {
    const int b2 = bid - 40960;
    const int hd0 = (b2 & 3) * 32, t0 = ((b2 >> 2) & 15) * 32, bg = b2 >> 6;
    const int tx = tid & 31, ty = tid >> 5;
    const int b = bg >> 2, g = bg & 3;
    const unsigned short* src = qkv + (size_t)b * SS * NQKV + 2560 + g * HD;
    #pragma unroll
    for (int j = 0; j < 32; j += 8)
      tileV[ty + j][tx] = src[(size_t)(t0 + ty + j) * NQKV + hd0 + tx];
    __syncthreads();
    unsigned short* dst = vt + (size_t)bg * HD * SS;
    #pragma unroll
    for (int j = 0; j < 32; j += 8)
      dst[(size_t)(hd0 + ty + j) * SS + t0 + tx] = tileV[tx][ty + j];
  }
}

// ---------------- MFMA flash attention ----------------
__global__ __launch_bounds__(256, 4) void fattn_kernel(
    const unsigned short* __restrict__ qkv,
    const unsigned short* __restrict__ vtb,
    unsigned short* __restrict__ aout)
{
  __shared__ unsigned short sK[64 * 128];     // 16 KB
  __shared__ unsigned short sV[128 * 64];     // 16 KB
  __shared__ unsigned short sP[4][16 * 64];   //  8 KB

  const int lane = threadIdx.x & 63, wave = threadIdx.x >> 6;
  const int quad = lane >> 4, col = lane & 15;
  const int idx = blockIdx.x;
  const int qb = 7 - (idx >> 8);              // heavy (long-K) blocks first
  const int bh = idx & 255;
  const int b = bh >> 4, h = bh & 15, g = h >> 2;

  const int qrow = qb * 64 + wave * 16 + col;
  const unsigned short* qg = qkv + ((size_t)(b * SS + qrow)) * NQKV + h * HD + quad * 8;
  short8 qf[4];
  #pragma unroll
  for (int c = 0; c < 4; ++c) qf[c] = *(const short8*)(qg + c * 32);

  const unsigned short* kg = qkv + (size_t)b * SS * NQKV + 2048 + g * HD;
  const unsigned short* vg = vtb + ((size_t)(b * GG + g)) * HD * SS;

  floatx4 acc_o[8];
  #pragma unroll
  for (int i = 0; i < 8; ++i) acc_o[i] = (floatx4){0.f, 0.f, 0.f, 0.f};
  float m[4] = {-INFINITY, -INFINITY, -INFINITY, -INFINITY};
  float l[4] = {0.f, 0.f, 0.f, 0.f};

  for (int kt = 0; kt <= qb; ++kt) {
    const int t0 = kt * 64;
    #pragma unroll
    for (int c = 0; c < 4; ++c) {
      const int ci = c * 4 + wave;
      { const int r  = ci * 4 + (lane >> 4);
        const int gl = (lane & 15) ^ (r & 15);
        async_copy16(kg + (size_t)(t0 + r) * NQKV + gl * 8, &sK[ci * 512]); }
      { const int r  = ci * 8 + (lane >> 3);
        const int gl = (lane & 7) ^ (r & 7);
        async_copy16(vg + (size_t)r * SS + t0 + gl * 8, &sV[ci * 512]); }
    }
    __syncthreads();

    floatx4 sc[4];
    #pragma unroll
    for (int s = 0; s < 4; ++s) sc[s] = (floatx4){0.f, 0.f, 0.f, 0.f};
    #pragma unroll
    for (int s = 0; s < 4; ++s) {
      const int trow = s * 16 + col;
      #pragma unroll
      for (int c = 0; c < 4; ++c) {
        const int p = (c * 4 + quad) ^ (trow & 15);
        const short8 kf = *(const short8*)(&sK[trow * 128 + p * 8]);
        sc[s] = __builtin_amdgcn_mfma_f32_16x16x32_bf16(qf[c], kf, sc[s], 0, 0, 0);
      }
    }

    if (kt == qb) {
      #pragma unroll
      for (int s = 0; s < 4; ++s)
        #pragma unroll
        for (int r = 0; r < 4; ++r)
          if (s * 16 + col > wave * 16 + quad * 4 + r) sc[s][r] = -1e30f;
    }

    float mx[4], alpha[4], lsum[4];
    #pragma unroll
    for (int r = 0; r < 4; ++r) {
      mx[r] = fmaxf(fmaxf(sc[0][r], sc[1][r]), fmaxf(sc[2][r], sc[3][r]));
      #pragma unroll
      for (int off = 8; off; off >>= 1) mx[r] = fmaxf(mx[r], __shfl_xor(mx[r], off, 16));
      mx[r] = fmaxf(mx[r], m[r]);
      alpha[r] = __expf(m[r] - mx[r]);
      m[r] = mx[r];
      lsum[r] = 0.f;
    }
    #pragma unroll
    for (int s = 0; s < 4; ++s)
      #pragma unroll
      for (int r = 0; r < 4; ++r) {
        const float p = __expf(sc[s][r] - m[r]);
        lsum[r] += p;
        const int row = quad * 4 + r;
        const int slot = (s * 2 + (col >> 3)) ^ (row & 7);
        sP[wave][row * 64 + slot * 8 + (col & 7)] = f2bf(p);
      }
    #pragma unroll
    for (int r = 0; r < 4; ++r) {
      #pragma unroll
      for (int off = 8; off; off >>= 1) lsum[r] += __shfl_xor(lsum[r], off, 16);
      l[r] = l[r] * alpha[r] + lsum[r];
    }
    #pragma unroll
    for (int n = 0; n < 8; ++n)
      #pragma unroll
      for (int r = 0; r < 4; ++r) acc_o[n][r] *= alpha[r];

    __asm__ volatile("s_waitcnt lgkmcnt(0)" ::: "memory");

    short8 pf[2];
    #pragma unroll
    for (int kc = 0; kc < 2; ++kc)
      pf[kc] = *(const short8*)(&sP[wave][col * 64 + ((kc * 4 + quad) ^ (col & 7)) * 8]);
    #pragma unroll
    for (int n = 0; n < 8; ++n) {
      const int hdrow = n * 16 + col;
      #pragma unroll
      for (int kc = 0; kc < 2; ++kc) {
        const int p = (kc * 4 + quad) ^ (hdrow & 7);
        const short8 vf = *(const short8*)(&sV[hdrow * 64 + p * 8]);
        acc_o[n] = __builtin_amdgcn_mfma_f32_16x16x32_bf16(pf[kc], vf, acc_o[n], 0, 0, 0);
      }
    }
    __syncthreads();
  }

  float inv[4];
  #pragma unroll
  for (int r = 0; r < 4; ++r) inv[r] = 1.f / l[r];
  unsigned short* ob = aout + ((size_t)(b * SS + qb * 64 + wave * 16)) * DD + h * HD;
  #pragma unroll
  for (int n = 0; n < 8; ++n)
    #pragma unroll
    for (int r = 0; r < 4; ++r)
      ob[(size_t)(quad * 4 + r) * DD + n * 16 + col] = f2bf(acc_o[n][r] * inv[r]);
}

extern "C" void kernel_launch(void* const* d_in, const int* in_sizes, int n_in,
                              void* d_out, int out_size, void* d_ws, size_t ws_size,
                              hipStream_t stream) {
  const float* x   = (const float*)d_in[0];
  const float* Wq  = (const float*)d_in[1];
  const float* bq  = (const float*)d_in[2];
  const float* Wk  = (const float*)d_in[3];
  const float* bk  = (const float*)d_in[4];
  const float* Wv  = (const float*)d_in[5];
  const float* bv  = (const float*)d_in[6];
  const float* Wo  = (const float*)d_in[7];
  const float* bo  = (const float*)d_in[8];
  const float* qns = (const float*)d_in[9];
  const float* kns = (const float*)d_in[10];

  char* ws = (char*)d_ws;
  unsigned short* xb    = (unsigned short*)(ws);                 // 8192x2048 bf16 (dead after QKV gemm)
  unsigned short* vtb   = (unsigned short*)(ws);                 // 16x4x128x512 bf16 (reuses xb)
  unsigned short* WqkvT = (unsigned short*)(ws + 33554432);      // 3072x2048 bf16
  unsigned short* WoT   = (unsigned short*)(ws + 46137344);      // 2048x2048 bf16
  float*          bqkv  = (float*)         (ws + 54525952);      // 3072 f32
  unsigned short* qkv   = (unsigned short*)(ws + 54538240);      // 8192x3072 bf16
  unsigned short* aout  = (unsigned short*)(ws + 104869888);     // 8192x2048 bf16

  prep_kernel<<<PB_ALL, 256, 0, stream>>>(x, Wq, Wk, Wv, Wo, bq, bk, bv,
                                          xb, WqkvT, WoT, bqkv);
  // QKV: M=8192 N=3072 K=2048 -> 32x12 = 384 blocks (384%8==0)
  gemm256_kernel<true><<<384, 512, 0, stream>>>(xb, WqkvT, qkv, bqkv,
                                                NQKV, DD, NQKV);
  norm_vtr_kernel<<<45056, 256, 0, stream>>>(qkv, qns, kns, vtb);
  fattn_kernel<<<2048, 256, 0, stream>>>(qkv, vtb, aout);
  // O: M=8192 N=2048 K=2048 -> 32x8 = 256 blocks (256%8==0)
  gemm256_kernel<false><<<256, 512, 0, stream>>>(aout, WoT, d_out, bo,
                                                 DD, DD, DD);
  (void)in_sizes; (void)n_in; (void)out_size; (void)ws_size;
}

// Round 2
// 425.993 us; speedup vs baseline: 1.0241x; 1.0241x over previous
//
#include <hip/hip_runtime.h>
#include <stdint.h>

typedef __attribute__((ext_vector_type(4))) float floatx4;
typedef __attribute__((ext_vector_type(16))) float floatx16;
typedef __attribute__((ext_vector_type(8))) short short8;

// Problem constants
#define BB 16
#define SS 512
#define DD 2048
#define HH_ 16
#define HD 128
#define GG 4
#define MM (BB*SS)          // 8192
#define NQKV 3072           // 2048 q + 512 k + 512 v

__device__ __forceinline__ unsigned short f2bf(float f){
  unsigned u = __builtin_bit_cast(unsigned, f);
  u += 0x7fffu + ((u >> 16) & 1u);            // RNE
  return (unsigned short)(u >> 16);
}
__device__ __forceinline__ float bf2f_lo(unsigned d){
  return __builtin_bit_cast(float, d << 16);
}
__device__ __forceinline__ float bf2f_hi(unsigned d){
  return __builtin_bit_cast(float, d & 0xffff0000u);
}

// NOTE: LDS dest must be WAVE-UNIFORM; HW writes base + lane*16.
__device__ __forceinline__ void async_copy16(const void* g, void* l){
  __builtin_amdgcn_global_load_lds((const __attribute__((address_space(1))) unsigned*)g,
                                   (__attribute__((address_space(3))) unsigned*)l,
                                   16, 0, 0);
}

// ---------------- fused prep: cvt_x | 4x transpose | bias concat ----------------
#define PB_CVT   16384
#define PB_TRQ   (PB_CVT + 4096)
#define PB_TRK   (PB_TRQ + 1024)
#define PB_TRV   (PB_TRK + 1024)
#define PB_TRO   (PB_TRV + 4096)
#define PB_ALL   (PB_TRO + 12)

__global__ __launch_bounds__(256) void prep_kernel(
    const float* __restrict__ x,
    const float* __restrict__ Wq, const float* __restrict__ Wk,
    const float* __restrict__ Wv, const float* __restrict__ Wo,
    const float* __restrict__ bq, const float* __restrict__ bk,
    const float* __restrict__ bv,
    unsigned short* __restrict__ xb, unsigned short* __restrict__ WqkvT,
    unsigned short* __restrict__ WoT, float* __restrict__ bqkv)
{
  __shared__ float tile[32][33];
  const int bid = blockIdx.x, tid = threadIdx.x;

  if (bid < PB_CVT) {                       // ---- x fp32 -> bf16 ----
    const int i = bid * 256 + tid;
    float4 f = ((const float4*)x)[i];
    ushort4 o;
    o.x = f2bf(f.x); o.y = f2bf(f.y); o.z = f2bf(f.z); o.w = f2bf(f.w);
    ((ushort4*)xb)[i] = o;
    return;
  }
  if (bid < PB_TRO) {                       // ---- W transpose+cvt ----
    const float* src; unsigned short* dst; int R, C, b2;
    if (bid < PB_TRQ)      { src = Wq; dst = WqkvT;                          R = 2048; C = 2048; b2 = bid - PB_CVT; }
    else if (bid < PB_TRK) { src = Wk; dst = WqkvT + (size_t)2048 * 2048;    R = 2048; C = 512;  b2 = bid - PB_TRQ; }
    else if (bid < PB_TRV) { src = Wv; dst = WqkvT + (size_t)2560 * 2048;    R = 2048; C = 512;  b2 = bid - PB_TRK; }
    else                   { src = Wo; dst = WoT;                            R = 2048; C = 2048; b2 = bid - PB_TRV; }
    const int nbx = C >> 5;
    const int c0 = (b2 % nbx) * 32, r0 = (b2 / nbx) * 32;
    const int tx = tid & 31, ty = tid >> 5;          // 32 x 8
    #pragma unroll
    for (int j = 0; j < 32; j += 8)
      tile[ty + j][tx] = src[(size_t)(r0 + ty + j) * C + (c0 + tx)];
    __syncthreads();
    #pragma unroll
    for (int j = 0; j < 32; j += 8)
      dst[(size_t)(c0 + ty + j) * R + (r0 + tx)] = f2bf(tile[tx][ty + j]);
    return;
  }
  {                                         // ---- bias concat ----
    const int i = (bid - PB_TRO) * 256 + tid;
    if (i < NQKV)
      bqkv[i] = (i < 2048) ? bq[i] : (i < 2560 ? bk[i - 2048] : bv[i - 2560]);
  }
}

// ---------------- 256x256 4-phase bf16 GEMM: C = A(MxK) @ Bt(NxK)^T + bias ----
// 8 waves (2Mx4N), wave tile 128x64, BK=64, 16x16x32 MFMA, acc[8][4].
// LDS: 4 half-slots per operand (parity ring), 128 KiB. Granule-XOR swizzle
// (slot g^(r&7)) applied by pre-swizzling the GLOBAL source of
// global_load_lds; un-applied on ds_read. ds_reads are compiler-visible
// loads: the backend inserts precise counted lgkmcnt per MFMA operand
// (do NOT force lgkmcnt(0) — that serializes LDS and MFMA bursts; R1 showed
// 3.7 TF/CU from exactly that).
//
// Per tile t (parity p=t&1), ONE barrier per phase; every STAGE follows a
// barrier that follows its target slot's last reads:
//  P0: read B01+A-lo (12)                      | MFMA Alo x B01 | barrier
//  P1: read B23 (4)                            | MFMA Alo x B23 | barrier
//      (B reads of tile t end here)
//  P2: read A-hi (8) | STAGE B01(t+2)          | MFMA Ahi x B01 | barrier
//      (A reads of tile t end here)
//  P3: STAGE A01(t+2) | vmcnt(8)               | MFMA Ahi x B23 | barrier
// vmcnt(8): keeps exactly tile t+2's 8 loads in flight; everything through
// tile t+1 has landed before any wave reads it (barrier after vmcnt).
template<bool OUT_BF16>
__global__ __launch_bounds__(512, 2) void gemm256_kernel(
    const unsigned short* __restrict__ A,
    const unsigned short* __restrict__ Bt,
    void* __restrict__ Cout,
    const float* __restrict__ bias,
    int N, int K, int ldc)
{
  __shared__ unsigned short sA[4 * 128 * 64];   // 64 KB: 4 half-slots
  __shared__ unsigned short sB[4 * 128 * 64];   // 64 KB

  const int tid  = threadIdx.x;
  const int wave = tid >> 6, lane = tid & 63;
  const int wm = wave >> 2, wn = wave & 3;      // 2 x 4 wave grid
  const int l15 = lane & 15, l7 = lane & 7, q4 = lane >> 4;

  // bijective XCD swizzle (grid % 8 == 0 for both call sites)
  const int nbn = N >> 8;
  const int cpx = gridDim.x >> 3;
  const int bid = (blockIdx.x & 7) * cpx + (blockIdx.x >> 3);
  const int m0 = (bid / nbn) * 256;
  const int n0 = (bid % nbn) * 256;

  // staging: each STAGE covers 128 rows (2 x async_copy16); wave w writes
  // rows [w*8,w*8+8) (+64); lane l -> row w*8+(l>>3), slot l&7, fetches
  // logical granule (l&7)^(row&7)
  const int rowOff = wave * 8 + (lane >> 3);
  const int glog   = l7 ^ ((lane >> 3) & 7);
  const unsigned short* gA = A  + (size_t)(m0 + rowOff) * K + glog * 8;
  const unsigned short* gB = Bt + (size_t)(n0 + rowOff) * K + glog * 8;

#define STAGE_A(j, tt) do { \
    unsigned short* d_ = &sA[(2 * ((tt) & 1) + (j)) * 8192 + wave * 512]; \
    const unsigned short* s_ = gA + (size_t)((j) * 128) * K + (tt) * 64; \
    async_copy16(s_, d_); \
    async_copy16(s_ + (size_t)64 * K, d_ + 4096); } while (0)
#define STAGE_B(j, tt) do { \
    unsigned short* d_ = &sB[(2 * ((tt) & 1) + (j)) * 8192 + wave * 512]; \
    const unsigned short* s_ = gB + (size_t)((j) * 128) * K + (tt) * 64; \
    async_copy16(s_, d_); \
    async_copy16(s_ + (size_t)64 * K, d_ + 4096); } while (0)
#define FENCE() asm volatile("" ::: "memory")
#define BAR()   do { FENCE(); __builtin_amdgcn_s_barrier(); FENCE(); } while (0)

  // prologue: stage tiles 0 and 1 (16 loads), wait for tile 0's 8.
  STAGE_B(0, 0); STAGE_B(1, 0); STAGE_A(0, 0); STAGE_A(1, 0);
  STAGE_B(0, 1); STAGE_B(1, 1); STAGE_A(0, 1); STAGE_A(1, 1);

  floatx16 zero16 = {0.f};
  floatx4 acc[8][4];
  #pragma unroll
  for (int i = 0; i < 8; ++i)
    #pragma unroll
    for (int j = 0; j < 4; ++j)
      acc[i][j] = (floatx4){0.f, 0.f, 0.f, 0.f};
  (void)zero16;

  asm volatile("s_waitcnt vmcnt(8)" ::: "memory");
  BAR();

  short8 aF[4][2], bF[4][2];
  const int NT = K >> 6;

  // per-thread LDS read bases; frag: row = base + f*16 + l15,
  // k-chunk kk granule = kk*4 + q4, phys slot = granule ^ (row&7) = ^l7
  const unsigned short* pA = &sA[l15 * 64];
  const unsigned short* pB = &sB[((wn & 1) * 64 + l15) * 64];
  const int g0 = ((0 + q4) ^ l7) * 8;
  const int g1 = ((4 + q4) ^ l7) * 8;

#define LDA_(fa_, rb_, sa_) do { \
    aF[fa_][0] = *(const short8*)(pA + (sa_) * 8192 + ((rb_) + (fa_) * 16) * 64 + g0); \
    aF[fa_][1] = *(const short8*)(pA + (sa_) * 8192 + ((rb_) + (fa_) * 16) * 64 + g1); } while (0)
#define LDB_(fb_, sb_) do { \
    bF[fb_][0] = *(const short8*)(pB + (sb_) * 8192 + (fb_) * 16 * 64 + g0); \
    bF[fb_][1] = *(const short8*)(pB + (sb_) * 8192 + (fb_) * 16 * 64 + g1); } while (0)
#define MFMA_Q(fa0, fb0) \
    _Pragma("unroll") \
    for (int fa = 0; fa < 4; ++fa) { \
      _Pragma("unroll") \
      for (int fb = 0; fb < 2; ++fb) { \
        acc[(fa0)+fa][(fb0)+fb] = __builtin_amdgcn_mfma_f32_16x16x32_bf16(aF[fa][0], bF[(fb0)+fb][0], acc[(fa0)+fa][(fb0)+fb], 0, 0, 0); \
        acc[(fa0)+fa][(fb0)+fb] = __builtin_amdgcn_mfma_f32_16x16x32_bf16(aF[fa][1], bF[(fb0)+fb][1], acc[(fa0)+fa][(fb0)+fb], 0, 0, 0); \
      } \
    }

  #pragma unroll 1
  for (int t = 0; t < NT; ++t) {
    const int sa = 2 * (t & 1) + wm;        // this wave's A half-slot
    const int sb = 2 * (t & 1) + (wn >> 1); // this wave's B half-slot
    // ---- P0: B01 + A-lo reads, MFMA lo x B01 ----
    LDB_(0, sb); LDB_(1, sb);
    LDA_(0, 0, sa); LDA_(1, 0, sa); LDA_(2, 0, sa); LDA_(3, 0, sa);
    __builtin_amdgcn_s_setprio(1);
    MFMA_Q(0, 0);
    __builtin_amdgcn_s_setprio(0);
    BAR();
    // ---- P1: B23 reads, MFMA lo x B23 ----
    LDB_(2, sb); LDB_(3, sb);
    __builtin_amdgcn_s_setprio(1);
    MFMA_Q(0, 2);
    __builtin_amdgcn_s_setprio(0);
    BAR();                                  // B reads of tile t complete
    // ---- P2: A-hi reads, stage B01(t+2), MFMA hi x B01 ----
    LDA_(0, 64, sa); LDA_(1, 64, sa); LDA_(2, 64, sa); LDA_(3, 64, sa);
    if (t + 2 < NT) { STAGE_B(0, t + 2); STAGE_B(1, t + 2); }
    __builtin_amdgcn_s_setprio(1);
    MFMA_Q(4, 0);
    __builtin_amdgcn_s_setprio(0);
    BAR();                                  // A reads of tile t complete
    // ---- P3: stage A01(t+2), vmcnt, MFMA hi x B23 ----
    if (t + 2 < NT) {
      STAGE_A(0, t + 2); STAGE_A(1, t + 2);
      asm volatile("s_waitcnt vmcnt(8)" ::: "memory");   // tile t+1 landed
    } else if (t + 1 < NT) {
      asm volatile("s_waitcnt vmcnt(0)" ::: "memory");   // tail drain
    }
    __builtin_amdgcn_s_setprio(1);
    MFMA_Q(4, 2);
    __builtin_amdgcn_s_setprio(0);
    BAR();
  }
#undef STAGE_A
#undef STAGE_B
#undef LDA_
#undef LDB_
#undef MFMA_Q
#undef FENCE
#undef BAR

  // epilogue: 16x16 C/D layout: col(N) = l15 (B index), row(M) = q4*4+reg (A)
  const int r4 = q4 * 4;
  #pragma unroll
  for (int fb = 0; fb < 4; ++fb) {
    const int col = n0 + wn * 64 + fb * 16 + l15;
    const float bval = bias[col];
    #pragma unroll
    for (int fa = 0; fa < 8; ++fa) {
      const size_t rowb = (size_t)(m0 + wm * 128 + fa * 16 + r4);
      #pragma unroll
      for (int r = 0; r < 4; ++r) {
        const float v = acc[fa][fb][r] + bval;
        if (OUT_BF16)
          ((unsigned short*)Cout)[(rowb + r) * ldc + col] = f2bf(v);
        else
          ((float*)Cout)[(rowb + r) * ldc + col] = v;
      }
    }
  }
}

// ---------------- fused RMSNorm+RoPE (q,k) | V transpose ----------------
__global__ __launch_bounds__(256) void norm_vtr_kernel(
    unsigned short* __restrict__ qkv,
    const float* __restrict__ qs, const float* __restrict__ ks,
    unsigned short* __restrict__ vt)
{
  __shared__ unsigned short tileV[32][34];
  const int bid = blockIdx.x, tid = threadIdx.x;

  if (bid < 40960) {
    const int wave = tid >> 6, lane = tid & 63;
    const int gw  = bid * 4 + wave;
    const int row = gw / 20;
    const int hh  = gw % 20;          // 0..15 q heads, 16..19 k heads
    const bool isq = hh < 16;

    unsigned* p = (unsigned*)(qkv + (size_t)row * NQKV + hh * 128) + lane;
    unsigned d = *p;
    float x1 = bf2f_lo(d), x2 = bf2f_hi(d);

    float ss = x1 * x1 + x2 * x2;
    #pragma unroll
    for (int off = 32; off; off >>= 1) ss += __shfl_xor(ss, off, 64);
    const float r = rsqrtf(ss * (1.f / 128.f) + 1e-6f);

    const float2 sc = ((const float2*)(isq ? qs : ks))[lane];
    float n1 = x1 * r * sc.x;
    float n2 = x2 * r * sc.y;

    const float t = (float)(row & (SS - 1));
    const float freq = __expf((float)lane * (-2.f / 128.f) * 9.21034037197618f);
    float sn, cs;
    __sincosf(t * freq, &sn, &cs);
    float o1 = n1 * cs - n2 * sn;
    float o2 = n1 * sn + n2 * cs;
    if (isq) { o1 *= (1.f / 128.f); o2 *= (1.f / 128.f); }

    *p = (unsigned)f2bf(o1) | ((unsigned)f2bf(o2) << 16);
    return;
  }
  {
    const int b2 = bid - 40960;
    const int hd0 = (b2 & 3) * 32, t0 = ((b2 >> 2) & 15) * 32, bg = b2 >> 6;
    const int tx = tid & 31, ty = tid >> 5;
    const int b = bg >> 2, g = bg & 3;
    const unsigned short* src = qkv + (size_t)b * SS * NQKV + 2560 + g * HD;
    #pragma unroll
    for (int j = 0; j < 32; j += 8)
      tileV[ty + j][tx] = src[(size_t)(t0 + ty + j) * NQKV + hd0 + tx];
    __syncthreads();
    unsigned short* dst = vt + (size_t)bg * HD * SS;
    #pragma unroll
    for (int j = 0; j < 32; j += 8)
      dst[(size_t)(hd0 + ty + j) * SS + t0 + tx] = tileV[tx][ty + j];
  }
}

// ---------------- MFMA flash attention ----------------
__global__ __launch_bounds__(256, 4) void fattn_kernel(
    const unsigned short* __restrict__ qkv,
    const unsigned short* __restrict__ vtb,
    unsigned short* __restrict__ aout)
{
  __shared__ unsigned short sK[64 * 128];     // 16 KB
  __shared__ unsigned short sV[128 * 64];     // 16 KB
  __shared__ unsigned short sP[4][16 * 64];   //  8 KB

  const int lane = threadIdx.x & 63, wave = threadIdx.x >> 6;
  const int quad = lane >> 4, col = lane & 15;
  const int idx = blockIdx.x;
  const int qb = 7 - (idx >> 8);              // heavy (long-K) blocks first
  const int bh = idx & 255;
  const int b = bh >> 4, h = bh & 15, g = h >> 2;

  const int qrow = qb * 64 + wave * 16 + col;
  const unsigned short* qg = qkv + ((size_t)(b * SS + qrow)) * NQKV + h * HD + quad * 8;
  short8 qf[4];
  #pragma unroll
  for (int c = 0; c < 4; ++c) qf[c] = *(const short8*)(qg + c * 32);

  const unsigned short* kg = qkv + (size_t)b * SS * NQKV + 2048 + g * HD;
  const unsigned short* vg = vtb + ((size_t)(b * GG + g)) * HD * SS;

  floatx4 acc_o[8];
  #pragma unroll
  for (int i = 0; i < 8; ++i) acc_o[i] = (floatx4){0.f, 0.f, 0.f, 0.f};
  float m[4] = {-INFINITY, -INFINITY, -INFINITY, -INFINITY};
  float l[4] = {0.f, 0.f, 0.f, 0.f};

  for (int kt = 0; kt <= qb; ++kt) {
    const int t0 = kt * 64;
    #pragma unroll
    for (int c = 0; c < 4; ++c) {
      const int ci = c * 4 + wave;
      { const int r  = ci * 4 + (lane >> 4);
        const int gl = (lane & 15) ^ (r & 15);
        async_copy16(kg + (size_t)(t0 + r) * NQKV + gl * 8, &sK[ci * 512]); }
      { const int r  = ci * 8 + (lane >> 3);
        const int gl = (lane & 7) ^ (r & 7);
        async_copy16(vg + (size_t)r * SS + t0 + gl * 8, &sV[ci * 512]); }
    }
    __syncthreads();

    floatx4 sc[4];
    #pragma unroll
    for (int s = 0; s < 4; ++s) sc[s] = (floatx4){0.f, 0.f, 0.f, 0.f};
    #pragma unroll
    for (int s = 0; s < 4; ++s) {
      const int trow = s * 16 + col;
      #pragma unroll
      for (int c = 0; c < 4; ++c) {
        const int p = (c * 4 + quad) ^ (trow & 15);
        const short8 kf = *(const short8*)(&sK[trow * 128 + p * 8]);
        sc[s] = __builtin_amdgcn_mfma_f32_16x16x32_bf16(qf[c], kf, sc[s], 0, 0, 0);
      }
    }

    if (kt == qb) {
      #pragma unroll
      for (int s = 0; s < 4; ++s)
        #pragma unroll
        for (int r = 0; r < 4; ++r)
          if (s * 16 + col > wave * 16 + quad * 4 + r) sc[s][r] = -1e30f;
    }

    float mx[4], alpha[4], lsum[4];
    #pragma unroll
    for (int r = 0; r < 4; ++r) {
      mx[r] = fmaxf(fmaxf(sc[0][r], sc[1][r]), fmaxf(sc[2][r], sc[3][r]));
      #pragma unroll
      for (int off = 8; off; off >>= 1) mx[r] = fmaxf(mx[r], __shfl_xor(mx[r], off, 16));
      mx[r] = fmaxf(mx[r], m[r]);
      alpha[r] = __expf(m[r] - mx[r]);
      m[r] = mx[r];
      lsum[r] = 0.f;
    }
    #pragma unroll
    for (int s = 0; s < 4; ++s)
      #pragma unroll
      for (int r = 0; r < 4; ++r) {
        const float p = __expf(sc[s][r] - m[r]);
        lsum[r] += p;
        const int row = quad * 4 + r;
        const int slot = (s * 2 + (col >> 3)) ^ (row & 7);
        sP[wave][row * 64 + slot * 8 + (col & 7)] = f2bf(p);
      }
    #pragma unroll
    for (int r = 0; r < 4; ++r) {
      #pragma unroll
      for (int off = 8; off; off >>= 1) lsum[r] += __shfl_xor(lsum[r], off, 16);
      l[r] = l[r] * alpha[r] + lsum[r];
    }
    #pragma unroll
    for (int n = 0; n < 8; ++n)
      #pragma unroll
      for (int r = 0; r < 4; ++r) acc_o[n][r] *= alpha[r];

    __asm__ volatile("s_waitcnt lgkmcnt(0)" ::: "memory");

    short8 pf[2];
    #pragma unroll
    for (int kc = 0; kc < 2; ++kc)
      pf[kc] = *(const short8*)(&sP[wave][col * 64 + ((kc * 4 + quad) ^ (col & 7)) * 8]);
    #pragma unroll
    for (int n = 0; n < 8; ++n) {
      const int hdrow = n * 16 + col;
      #pragma unroll
      for (int kc = 0; kc < 2; ++kc) {
        const int p = (kc * 4 + quad) ^ (hdrow & 7);
        const short8 vf = *(const short8*)(&sV[hdrow * 64 + p * 8]);
        acc_o[n] = __builtin_amdgcn_mfma_f32_16x16x32_bf16(pf[kc], vf, acc_o[n], 0, 0, 0);
      }
    }
    __syncthreads();
  }

  float inv[4];
  #pragma unroll
  for (int r = 0; r < 4; ++r) inv[r] = 1.f / l[r];
  unsigned short* ob = aout + ((size_t)(b * SS + qb * 64 + wave * 16)) * DD + h * HD;
  #pragma unroll
  for (int n = 0; n < 8; ++n)
    #pragma unroll
    for (int r = 0; r < 4; ++r)
      ob[(size_t)(quad * 4 + r) * DD + n * 16 + col] = f2bf(acc_o[n][r] * inv[r]);
}

extern "C" void kernel_launch(void* const* d_in, const int* in_sizes, int n_in,
                              void* d_out, int out_size, void* d_ws, size_t ws_size,
                              hipStream_t stream) {
  const float* x   = (const float*)d_in[0];
  const float* Wq  = (const float*)d_in[1];
  const float* bq  = (const float*)d_in[2];
  const float* Wk  = (const float*)d_in[3];
  const float* bk  = (const float*)d_in[4];
  const float* Wv  = (const float*)d_in[5];
  const float* bv  = (const float*)d_in[6];
  const float* Wo  = (const float*)d_in[7];
  const float* bo  = (const float*)d_in[8];
  const float* qns = (const float*)d_in[9];
  const float* kns = (const float*)d_in[10];

  char* ws = (char*)d_ws;
  unsigned short* xb    = (unsigned short*)(ws);                 // 8192x2048 bf16 (dead after QKV gemm)
  unsigned short* vtb   = (unsigned short*)(ws);                 // 16x4x128x512 bf16 (reuses xb)
  unsigned short* WqkvT = (unsigned short*)(ws + 33554432);      // 3072x2048 bf16
  unsigned short* WoT   = (unsigned short*)(ws + 46137344);      // 2048x2048 bf16
  float*          bqkv  = (float*)         (ws + 54525952);      // 3072 f32
  unsigned short* qkv   = (unsigned short*)(ws + 54538240);      // 8192x3072 bf16
  unsigned short* aout  = (unsigned short*)(ws + 104869888);     // 8192x2048 bf16

  prep_kernel<<<PB_ALL, 256, 0, stream>>>(x, Wq, Wk, Wv, Wo, bq, bk, bv,
                                          xb, WqkvT, WoT, bqkv);
  // QKV: M=8192 N=3072 K=2048 -> 32x12 = 384 blocks (384%8==0)
  gemm256_kernel<true><<<384, 512, 0, stream>>>(xb, WqkvT, qkv, bqkv,
                                                NQKV, DD, NQKV);
  norm_vtr_kernel<<<45056, 256, 0, stream>>>(qkv, qns, kns, vtb);
  fattn_kernel<<<2048, 256, 0, stream>>>(qkv, vtb, aout);
  // O: M=8192 N=2048 K=2048 -> 32x8 = 256 blocks (256%8==0)
  gemm256_kernel<false><<<256, 512, 0, stream>>>(aout, WoT, d_out, bo,
                                                 DD, DD, DD);
  (void)in_sizes; (void)n_in; (void)out_size; (void)ws_size;
}

// Round 3
// 420.376 us; speedup vs baseline: 1.0378x; 1.0134x over previous
//
#include <hip/hip_runtime.h>
#include <stdint.h>

typedef __attribute__((ext_vector_type(4))) float floatx4;
typedef __attribute__((ext_vector_type(16))) float floatx16;
typedef __attribute__((ext_vector_type(8))) short short8;

// Problem constants
#define BB 16
#define SS 512
#define DD 2048
#define HH_ 16
#define HD 128
#define GG 4
#define MM (BB*SS)          // 8192
#define NQKV 3072           // 2048 q + 512 k + 512 v

__device__ __forceinline__ unsigned short f2bf(float f){
  unsigned u = __builtin_bit_cast(unsigned, f);
  u += 0x7fffu + ((u >> 16) & 1u);            // RNE
  return (unsigned short)(u >> 16);
}
__device__ __forceinline__ float bf2f_lo(unsigned d){
  return __builtin_bit_cast(float, d << 16);
}
__device__ __forceinline__ float bf2f_hi(unsigned d){
  return __builtin_bit_cast(float, d & 0xffff0000u);
}

// NOTE: LDS dest must be WAVE-UNIFORM; HW writes base + lane*16.
__device__ __forceinline__ void async_copy16(const void* g, void* l){
  __builtin_amdgcn_global_load_lds((const __attribute__((address_space(1))) unsigned*)g,
                                   (__attribute__((address_space(3))) unsigned*)l,
                                   16, 0, 0);
}

// ---------------- fused prep: cvt_x | 4x transpose | bias concat ----------------
#define PB_CVT   16384
#define PB_TRQ   (PB_CVT + 4096)
#define PB_TRK   (PB_TRQ + 1024)
#define PB_TRV   (PB_TRK + 1024)
#define PB_TRO   (PB_TRV + 4096)
#define PB_ALL   (PB_TRO + 12)

__global__ __launch_bounds__(256) void prep_kernel(
    const float* __restrict__ x,
    const float* __restrict__ Wq, const float* __restrict__ Wk,
    const float* __restrict__ Wv, const float* __restrict__ Wo,
    const float* __restrict__ bq, const float* __restrict__ bk,
    const float* __restrict__ bv,
    unsigned short* __restrict__ xb, unsigned short* __restrict__ WqkvT,
    unsigned short* __restrict__ WoT, float* __restrict__ bqkv)
{
  __shared__ float tile[32][33];
  const int bid = blockIdx.x, tid = threadIdx.x;

  if (bid < PB_CVT) {                       // ---- x fp32 -> bf16 ----
    const int i = bid * 256 + tid;
    float4 f = ((const float4*)x)[i];
    ushort4 o;
    o.x = f2bf(f.x); o.y = f2bf(f.y); o.z = f2bf(f.z); o.w = f2bf(f.w);
    ((ushort4*)xb)[i] = o;
    return;
  }
  if (bid < PB_TRO) {                       // ---- W transpose+cvt ----
    const float* src; unsigned short* dst; int R, C, b2;
    if (bid < PB_TRQ)      { src = Wq; dst = WqkvT;                          R = 2048; C = 2048; b2 = bid - PB_CVT; }
    else if (bid < PB_TRK) { src = Wk; dst = WqkvT + (size_t)2048 * 2048;    R = 2048; C = 512;  b2 = bid - PB_TRQ; }
    else if (bid < PB_TRV) { src = Wv; dst = WqkvT + (size_t)2560 * 2048;    R = 2048; C = 512;  b2 = bid - PB_TRK; }
    else                   { src = Wo; dst = WoT;                            R = 2048; C = 2048; b2 = bid - PB_TRV; }
    const int nbx = C >> 5;
    const int c0 = (b2 % nbx) * 32, r0 = (b2 / nbx) * 32;
    const int tx = tid & 31, ty = tid >> 5;          // 32 x 8
    #pragma unroll
    for (int j = 0; j < 32; j += 8)
      tile[ty + j][tx] = src[(size_t)(r0 + ty + j) * C + (c0 + tx)];
    __syncthreads();
    #pragma unroll
    for (int j = 0; j < 32; j += 8)
      dst[(size_t)(c0 + ty + j) * R + (r0 + tx)] = f2bf(tile[tx][ty + j]);
    return;
  }
  {                                         // ---- bias concat ----
    const int i = (bid - PB_TRO) * 256 + tid;
    if (i < NQKV)
      bqkv[i] = (i < 2048) ? bq[i] : (i < 2560 ? bk[i - 2048] : bv[i - 2560]);
  }
}

// ---------------- bf16 GEMM (128x128, m97 structure): C = A @ Bt^T + bias ----
// Proven at 117.5us for QKV (R0). 256 threads, BK=64, 32x32x16 MFMA 2x2/wave.
// LDS granule-XOR swizzle via pre-swizzled global source of global_load_lds.
template<bool OUT_BF16>
__global__ __launch_bounds__(256) void gemm_bt_kernel(
    const unsigned short* __restrict__ A,
    const unsigned short* __restrict__ Bt,
    void* __restrict__ Cout,
    const float* __restrict__ bias,
    int M, int N, int K, int ldc)
{
  __shared__ unsigned short sA[128 * 64];   // 16 KB
  __shared__ unsigned short sB[128 * 64];   // 16 KB
  const int tid  = threadIdx.x;
  const int wave = tid >> 6;
  const int lane = tid & 63;
  const int m0 = blockIdx.y * 128;
  const int n0 = blockIdx.x * 128;
  const int wm = (wave >> 1) * 64;
  const int wn = (wave & 1) * 64;

  floatx16 acc[2][2];
  #pragma unroll
  for (int i = 0; i < 2; i++)
    #pragma unroll
    for (int j = 0; j < 2; j++)
      #pragma unroll
      for (int r = 0; r < 16; r++) acc[i][j][r] = 0.f;

  const int sglog = (lane & 7) ^ ((lane >> 3) & 7);
  const unsigned short* gA = A  + (size_t)(m0 + 32 * wave + (lane >> 3)) * K + sglog * 8;
  const unsigned short* gB = Bt + (size_t)(n0 + 32 * wave + (lane >> 3)) * K + sglog * 8;
  unsigned short* lA = &sA[32 * wave * 64];   // wave-uniform; HW adds lane*16B
  unsigned short* lB = &sB[32 * wave * 64];

  for (int k0 = 0; k0 < K; k0 += 64) {
    #pragma unroll
    for (int c = 0; c < 4; ++c) {
      async_copy16(gA + (size_t)c * 8 * K + k0, lA + c * 512);
      async_copy16(gB + (size_t)c * 8 * K + k0, lB + c * 512);
    }
    __syncthreads();

    #pragma unroll
    for (int kh = 0; kh < 4; ++kh) {
      const int slot = (kh * 2 + (lane >> 5)) ^ (lane & 7);
      short8 aF[2], bF[2];
      #pragma unroll
      for (int i = 0; i < 2; ++i)
        aF[i] = *(const short8*)(&sA[(wm + i * 32 + (lane & 31)) * 64 + slot * 8]);
      #pragma unroll
      for (int j = 0; j < 2; ++j)
        bF[j] = *(const short8*)(&sB[(wn + j * 32 + (lane & 31)) * 64 + slot * 8]);
      #pragma unroll
      for (int i = 0; i < 2; ++i)
        #pragma unroll
        for (int j = 0; j < 2; ++j)
          acc[i][j] = __builtin_amdgcn_mfma_f32_32x32x16_bf16(aF[i], bF[j], acc[i][j], 0, 0, 0);
    }
    __syncthreads();
  }

  const int cc = lane & 31;
  const int rb = 4 * (lane >> 5);
  #pragma unroll
  for (int j = 0; j < 2; j++) {
    const int col = n0 + wn + j * 32 + cc;
    const float bval = bias[col];
    #pragma unroll
    for (int i = 0; i < 2; i++) {
      #pragma unroll
      for (int reg = 0; reg < 16; reg++) {
        const int row = m0 + wm + i * 32 + (reg & 3) + 8 * (reg >> 2) + rb;
        const float v = acc[i][j][reg] + bval;
        if (OUT_BF16)
          ((unsigned short*)Cout)[(size_t)row * ldc + col] = f2bf(v);
        else
          ((float*)Cout)[(size_t)row * ldc + col] = v;
      }
    }
  }
}

// ---------------- 256x256 4-phase bf16 GEMM (used for O proj: 256 blocks =
// exactly 1 round at 1 block/CU). Verified correct in R2.
template<bool OUT_BF16>
__global__ __launch_bounds__(512, 2) void gemm256_kernel(
    const unsigned short* __restrict__ A,
    const unsigned short* __restrict__ Bt,
    void* __restrict__ Cout,
    const float* __restrict__ bias,
    int N, int K, int ldc)
{
  __shared__ unsigned short sA[4 * 128 * 64];   // 64 KB: 4 half-slots
  __shared__ unsigned short sB[4 * 128 * 64];   // 64 KB

  const int tid  = threadIdx.x;
  const int wave = tid >> 6, lane = tid & 63;
  const int wm = wave >> 2, wn = wave & 3;      // 2 x 4 wave grid
  const int l15 = lane & 15, l7 = lane & 7, q4 = lane >> 4;

  const int nbn = N >> 8;
  const int cpx = gridDim.x >> 3;
  const int bid = (blockIdx.x & 7) * cpx + (blockIdx.x >> 3);
  const int m0 = (bid / nbn) * 256;
  const int n0 = (bid % nbn) * 256;

  const int rowOff = wave * 8 + (lane >> 3);
  const int glog   = l7 ^ ((lane >> 3) & 7);
  const unsigned short* gA = A  + (size_t)(m0 + rowOff) * K + glog * 8;
  const unsigned short* gB = Bt + (size_t)(n0 + rowOff) * K + glog * 8;

#define STAGE_A(j, tt) do { \
    unsigned short* d_ = &sA[(2 * ((tt) & 1) + (j)) * 8192 + wave * 512]; \
    const unsigned short* s_ = gA + (size_t)((j) * 128) * K + (tt) * 64; \
    async_copy16(s_, d_); \
    async_copy16(s_ + (size_t)64 * K, d_ + 4096); } while (0)
#define STAGE_B(j, tt) do { \
    unsigned short* d_ = &sB[(2 * ((tt) & 1) + (j)) * 8192 + wave * 512]; \
    const unsigned short* s_ = gB + (size_t)((j) * 128) * K + (tt) * 64; \
    async_copy16(s_, d_); \
    async_copy16(s_ + (size_t)64 * K, d_ + 4096); } while (0)
#define FENCE() asm volatile("" ::: "memory")
#define BAR()   do { FENCE(); __builtin_amdgcn_s_barrier(); FENCE(); } while (0)

  STAGE_B(0, 0); STAGE_B(1, 0); STAGE_A(0, 0); STAGE_A(1, 0);
  STAGE_B(0, 1); STAGE_B(1, 1); STAGE_A(0, 1); STAGE_A(1, 1);

  floatx4 acc[8][4];
  #pragma unroll
  for (int i = 0; i < 8; ++i)
    #pragma unroll
    for (int j = 0; j < 4; ++j)
      acc[i][j] = (floatx4){0.f, 0.f, 0.f, 0.f};

  asm volatile("s_waitcnt vmcnt(8)" ::: "memory");
  BAR();

  short8 aF[4][2], bF[4][2];
  const int NT = K >> 6;

  const unsigned short* pA = &sA[l15 * 64];
  const unsigned short* pB = &sB[((wn & 1) * 64 + l15) * 64];
  const int g0 = ((0 + q4) ^ l7) * 8;
  const int g1 = ((4 + q4) ^ l7) * 8;

#define LDA_(fa_, rb_, sa_) do { \
    aF[fa_][0] = *(const short8*)(pA + (sa_) * 8192 + ((rb_) + (fa_) * 16) * 64 + g0); \
    aF[fa_][1] = *(const short8*)(pA + (sa_) * 8192 + ((rb_) + (fa_) * 16) * 64 + g1); } while (0)
#define LDB_(fb_, sb_) do { \
    bF[fb_][0] = *(const short8*)(pB + (sb_) * 8192 + (fb_) * 16 * 64 + g0); \
    bF[fb_][1] = *(const short8*)(pB + (sb_) * 8192 + (fb_) * 16 * 64 + g1); } while (0)
#define MFMA_Q(fa0, fb0) \
    _Pragma("unroll") \
    for (int fa = 0; fa < 4; ++fa) { \
      _Pragma("unroll") \
      for (int fb = 0; fb < 2; ++fb) { \
        acc[(fa0)+fa][(fb0)+fb] = __builtin_amdgcn_mfma_f32_16x16x32_bf16(aF[fa][0], bF[(fb0)+fb][0], acc[(fa0)+fa][(fb0)+fb], 0, 0, 0); \
        acc[(fa0)+fa][(fb0)+fb] = __builtin_amdgcn_mfma_f32_16x16x32_bf16(aF[fa][1], bF[(fb0)+fb][1], acc[(fa0)+fa][(fb0)+fb], 0, 0, 0); \
      } \
    }

  #pragma unroll 1
  for (int t = 0; t < NT; ++t) {
    const int sa = 2 * (t & 1) + wm;
    const int sb = 2 * (t & 1) + (wn >> 1);
    // ---- P0 ----
    LDB_(0, sb); LDB_(1, sb);
    LDA_(0, 0, sa); LDA_(1, 0, sa); LDA_(2, 0, sa); LDA_(3, 0, sa);
    __builtin_amdgcn_s_setprio(1);
    MFMA_Q(0, 0);
    __builtin_amdgcn_s_setprio(0);
    BAR();
    // ---- P1 ----
    LDB_(2, sb); LDB_(3, sb);
    __builtin_amdgcn_s_setprio(1);
    MFMA_Q(0, 2);
    __builtin_amdgcn_s_setprio(0);
    BAR();
    // ---- P2 ----
    LDA_(0, 64, sa); LDA_(1, 64, sa); LDA_(2, 64, sa); LDA_(3, 64, sa);
    if (t + 2 < NT) { STAGE_B(0, t + 2); STAGE_B(1, t + 2); }
    __builtin_amdgcn_s_setprio(1);
    MFMA_Q(4, 0);
    __builtin_amdgcn_s_setprio(0);
    BAR();
    // ---- P3 ----
    if (t + 2 < NT) {
      STAGE_A(0, t + 2); STAGE_A(1, t + 2);
      asm volatile("s_waitcnt vmcnt(8)" ::: "memory");
    } else if (t + 1 < NT) {
      asm volatile("s_waitcnt vmcnt(0)" ::: "memory");
    }
    __builtin_amdgcn_s_setprio(1);
    MFMA_Q(4, 2);
    __builtin_amdgcn_s_setprio(0);
    BAR();
  }
#undef STAGE_A
#undef STAGE_B
#undef LDA_
#undef LDB_
#undef MFMA_Q
#undef FENCE
#undef BAR

  const int r4 = q4 * 4;
  #pragma unroll
  for (int fb = 0; fb < 4; ++fb) {
    const int col = n0 + wn * 64 + fb * 16 + l15;
    const float bval = bias[col];
    #pragma unroll
    for (int fa = 0; fa < 8; ++fa) {
      const size_t rowb = (size_t)(m0 + wm * 128 + fa * 16 + r4);
      #pragma unroll
      for (int r = 0; r < 4; ++r) {
        const float v = acc[fa][fb][r] + bval;
        if (OUT_BF16)
          ((unsigned short*)Cout)[(rowb + r) * ldc + col] = f2bf(v);
        else
          ((float*)Cout)[(rowb + r) * ldc + col] = v;
      }
    }
  }
}

// ---------------- fused RMSNorm+RoPE (q,k) | V transpose ----------------
__global__ __launch_bounds__(256) void norm_vtr_kernel(
    unsigned short* __restrict__ qkv,
    const float* __restrict__ qs, const float* __restrict__ ks,
    unsigned short* __restrict__ vt)
{
  __shared__ unsigned short tileV[32][34];
  const int bid = blockIdx.x, tid = threadIdx.x;

  if (bid < 40960) {
    const int wave = tid >> 6, lane = tid & 63;
    const int gw  = bid * 4 + wave;
    const int row = gw / 20;
    const int hh  = gw % 20;          // 0..15 q heads, 16..19 k heads
    const bool isq = hh < 16;

    unsigned* p = (unsigned*)(qkv + (size_t)row * NQKV + hh * 128) + lane;
    unsigned d = *p;
    float x1 = bf2f_lo(d), x2 = bf2f_hi(d);

    float ss = x1 * x1 + x2 * x2;
    #pragma unroll
    for (int off = 32; off; off >>= 1) ss += __shfl_xor(ss, off, 64);
    const float r = rsqrtf(ss * (1.f / 128.f) + 1e-6f);

    const float2 sc = ((const float2*)(isq ? qs : ks))[lane];
    float n1 = x1 * r * sc.x;
    float n2 = x2 * r * sc.y;

    const float t = (float)(row & (SS - 1));
    const float freq = __expf((float)lane * (-2.f / 128.f) * 9.21034037197618f);
    float sn, cs;
    __sincosf(t * freq, &sn, &cs);
    float o1 = n1 * cs - n2 * sn;
    float o2 = n1 * sn + n2 * cs;
    if (isq) { o1 *= (1.f / 128.f); o2 *= (1.f / 128.f); }

    *p = (unsigned)f2bf(o1) | ((unsigned)f2bf(o2) << 16);
    return;
  }
  {
    const int b2 = bid - 40960;
    const int hd0 = (b2 & 3) * 32, t0 = ((b2 >> 2) & 15) * 32, bg = b2 >> 6;
    const int tx = tid & 31, ty = tid >> 5;
    const int b = bg >> 2, g = bg & 3;
    const unsigned short* src = qkv + (size_t)b * SS * NQKV + 2560 + g * HD;
    #pragma unroll
    for (int j = 0; j < 32; j += 8)
      tileV[ty + j][tx] = src[(size_t)(t0 + ty + j) * NQKV + hd0 + tx];
    __syncthreads();
    unsigned short* dst = vt + (size_t)bg * HD * SS;
    #pragma unroll
    for (int j = 0; j < 32; j += 8)
      dst[(size_t)(hd0 + ty + j) * SS + t0 + tx] = tileV[tx][ty + j];
  }
}

// ---------------- MFMA flash attention, double-buffered K/V ----------------
// R2 counters: MfmaUtil 1.5%, VALUBusy 4%, HBM 9%, ~150us -> pure
// latency-bound: staging latency fully exposed per tile (single buffer,
// 2 barriers/tile, vmcnt(0) drain right after issue). Fix: sK/sV[2]
// (72 KB -> 2 blocks/CU), depth-1 prefetch, ONE __syncthreads per tile.
// At top of iter kt the syncthreads' per-wave vmcnt(0) retires copies
// issued a full compute phase earlier (near-free); stage(kt+1 -> buf^1)
// is issued after the barrier that follows all waves' reads of buf^1
// (tile kt-1) -> no WAR hazard.
__global__ __launch_bounds__(256, 2) void fattn_kernel(
    const unsigned short* __restrict__ qkv,
    const unsigned short* __restrict__ vtb,
    unsigned short* __restrict__ aout)
{
  __shared__ unsigned short sK[2][64 * 128];  // 32 KB
  __shared__ unsigned short sV[2][128 * 64];  // 32 KB
  __shared__ unsigned short sP[4][16 * 64];   //  8 KB  (72 KB total)

  const int lane = threadIdx.x & 63, wave = threadIdx.x >> 6;
  const int quad = lane >> 4, col = lane & 15;
  const int idx = blockIdx.x;
  const int qb = 7 - (idx >> 8);              // heavy (long-K) blocks first
  const int bh = idx & 255;
  const int b = bh >> 4, h = bh & 15, g = h >> 2;

  const int qrow = qb * 64 + wave * 16 + col;
  const unsigned short* qg = qkv + ((size_t)(b * SS + qrow)) * NQKV + h * HD + quad * 8;
  short8 qf[4];
  #pragma unroll
  for (int c = 0; c < 4; ++c) qf[c] = *(const short8*)(qg + c * 32);

  const unsigned short* kg = qkv + (size_t)b * SS * NQKV + 2048 + g * HD;
  const unsigned short* vg = vtb + ((size_t)(b * GG + g)) * HD * SS;

  floatx4 acc_o[8];
  #pragma unroll
  for (int i = 0; i < 8; ++i) acc_o[i] = (floatx4){0.f, 0.f, 0.f, 0.f};
  float m[4] = {-INFINITY, -INFINITY, -INFINITY, -INFINITY};
  float l[4] = {0.f, 0.f, 0.f, 0.f};

#define STAGE_KV(kt_, bf_) do { \
    const int t0_ = (kt_) * 64; \
    _Pragma("unroll") \
    for (int c = 0; c < 4; ++c) { \
      const int ci = c * 4 + wave; \
      { const int r_  = ci * 4 + (lane >> 4); \
        const int gl_ = (lane & 15) ^ (r_ & 15); \
        async_copy16(kg + (size_t)(t0_ + r_) * NQKV + gl_ * 8, &sK[bf_][ci * 512]); } \
      { const int r_  = ci * 8 + (lane >> 3); \
        const int gl_ = (lane & 7) ^ (r_ & 7); \
        async_copy16(vg + (size_t)r_ * SS + t0_ + gl_ * 8, &sV[bf_][ci * 512]); } \
    } } while (0)

  STAGE_KV(0, 0);

  for (int kt = 0; kt <= qb; ++kt) {
    const int buf = kt & 1;
    __syncthreads();                          // retires tile-kt copies; releases buf^1
    if (kt < qb) STAGE_KV(kt + 1, buf ^ 1);   // prefetch next tile

    floatx4 sc[4];
    #pragma unroll
    for (int s = 0; s < 4; ++s) sc[s] = (floatx4){0.f, 0.f, 0.f, 0.f};
    __builtin_amdgcn_s_setprio(1);
    #pragma unroll
    for (int s = 0; s < 4; ++s) {
      const int trow = s * 16 + col;
      #pragma unroll
      for (int c = 0; c < 4; ++c) {
        const int p = (c * 4 + quad) ^ (trow & 15);
        const short8 kf = *(const short8*)(&sK[buf][trow * 128 + p * 8]);
        sc[s] = __builtin_amdgcn_mfma_f32_16x16x32_bf16(qf[c], kf, sc[s], 0, 0, 0);
      }
    }
    __builtin_amdgcn_s_setprio(0);

    if (kt == qb) {
      #pragma unroll
      for (int s = 0; s < 4; ++s)
        #pragma unroll
        for (int r = 0; r < 4; ++r)
          if (s * 16 + col > wave * 16 + quad * 4 + r) sc[s][r] = -1e30f;
    }

    float mx[4], alpha[4], lsum[4];
    #pragma unroll
    for (int r = 0; r < 4; ++r) {
      mx[r] = fmaxf(fmaxf(sc[0][r], sc[1][r]), fmaxf(sc[2][r], sc[3][r]));
      #pragma unroll
      for (int off = 8; off; off >>= 1) mx[r] = fmaxf(mx[r], __shfl_xor(mx[r], off, 16));
      mx[r] = fmaxf(mx[r], m[r]);
      alpha[r] = __expf(m[r] - mx[r]);
      m[r] = mx[r];
      lsum[r] = 0.f;
    }
    // P write: row=quad*4+r, col_t=s*16+col; granule g=s*2+(col>>3), slot=g^(row&7)
    #pragma unroll
    for (int s = 0; s < 4; ++s)
      #pragma unroll
      for (int r = 0; r < 4; ++r) {
        const float p = __expf(sc[s][r] - m[r]);
        lsum[r] += p;
        const int row = quad * 4 + r;
        const int slot = (s * 2 + (col >> 3)) ^ (row & 7);
        sP[wave][row * 64 + slot * 8 + (col & 7)] = f2bf(p);
      }
    #pragma unroll
    for (int r = 0; r < 4; ++r) {
      #pragma unroll
      for (int off = 8; off; off >>= 1) lsum[r] += __shfl_xor(lsum[r], off, 16);
      l[r] = l[r] * alpha[r] + lsum[r];
    }
    #pragma unroll
    for (int n = 0; n < 8; ++n)
      #pragma unroll
      for (int r = 0; r < 4; ++r) acc_o[n][r] *= alpha[r];

    // P read (A-frag): m=col, k=kc*32+quad*8+j -> granule kc*4+quad, slot ^(m&7)
    // (sP write->read dep is wave-private; compiler inserts the lgkmcnt)
    short8 pf[2];
    #pragma unroll
    for (int kc = 0; kc < 2; ++kc)
      pf[kc] = *(const short8*)(&sP[wave][col * 64 + ((kc * 4 + quad) ^ (col & 7)) * 8]);
    __builtin_amdgcn_s_setprio(1);
    #pragma unroll
    for (int n = 0; n < 8; ++n) {
      const int hdrow = n * 16 + col;
      #pragma unroll
      for (int kc = 0; kc < 2; ++kc) {
        const int p = (kc * 4 + quad) ^ (hdrow & 7);
        const short8 vf = *(const short8*)(&sV[buf][hdrow * 64 + p * 8]);
        acc_o[n] = __builtin_amdgcn_mfma_f32_16x16x32_bf16(pf[kc], vf, acc_o[n], 0, 0, 0);
      }
    }
    __builtin_amdgcn_s_setprio(0);
  }
#undef STAGE_KV

  float inv[4];
  #pragma unroll
  for (int r = 0; r < 4; ++r) inv[r] = 1.f / l[r];
  unsigned short* ob = aout + ((size_t)(b * SS + qb * 64 + wave * 16)) * DD + h * HD;
  #pragma unroll
  for (int n = 0; n < 8; ++n)
    #pragma unroll
    for (int r = 0; r < 4; ++r)
      ob[(size_t)(quad * 4 + r) * DD + n * 16 + col] = f2bf(acc_o[n][r] * inv[r]);
}

extern "C" void kernel_launch(void* const* d_in, const int* in_sizes, int n_in,
                              void* d_out, int out_size, void* d_ws, size_t ws_size,
                              hipStream_t stream) {
  const float* x   = (const float*)d_in[0];
  const float* Wq  = (const float*)d_in[1];
  const float* bq  = (const float*)d_in[2];
  const float* Wk  = (const float*)d_in[3];
  const float* bk  = (const float*)d_in[4];
  const float* Wv  = (const float*)d_in[5];
  const float* bv  = (const float*)d_in[6];
  const float* Wo  = (const float*)d_in[7];
  const float* bo  = (const float*)d_in[8];
  const float* qns = (const float*)d_in[9];
  const float* kns = (const float*)d_in[10];

  char* ws = (char*)d_ws;
  unsigned short* xb    = (unsigned short*)(ws);                 // 8192x2048 bf16 (dead after QKV gemm)
  unsigned short* vtb   = (unsigned short*)(ws);                 // 16x4x128x512 bf16 (reuses xb)
  unsigned short* WqkvT = (unsigned short*)(ws + 33554432);      // 3072x2048 bf16
  unsigned short* WoT   = (unsigned short*)(ws + 46137344);      // 2048x2048 bf16
  float*          bqkv  = (float*)         (ws + 54525952);      // 3072 f32
  unsigned short* qkv   = (unsigned short*)(ws + 54538240);      // 8192x3072 bf16
  unsigned short* aout  = (unsigned short*)(ws + 104869888);     // 8192x2048 bf16

  prep_kernel<<<PB_ALL, 256, 0, stream>>>(x, Wq, Wk, Wv, Wo, bq, bk, bv,
                                          xb, WqkvT, WoT, bqkv);
  // QKV: 128^2 tiles (proven 117.5us): grid (N/128, M/128) = (24, 64)
  gemm_bt_kernel<true><<<dim3(24, 64), 256, 0, stream>>>(xb, WqkvT, qkv, bqkv,
                                                         MM, NQKV, DD, NQKV);
  norm_vtr_kernel<<<45056, 256, 0, stream>>>(qkv, qns, kns, vtb);
  fattn_kernel<<<2048, 256, 0, stream>>>(qkv, vtb, aout);
  // O: 256^2 4-phase, 256 blocks = exactly 1 round at 1 block/CU
  gemm256_kernel<false><<<256, 512, 0, stream>>>(aout, WoT, d_out, bo,
                                                 DD, DD, DD);
  (void)in_sizes; (void)n_in; (void)out_size; (void)ws_size;
}

// Round 4
// 409.709 us; speedup vs baseline: 1.0648x; 1.0260x over previous
//
#include <hip/hip_runtime.h>
#include <stdint.h>

typedef __attribute__((ext_vector_type(4))) float floatx4;
typedef __attribute__((ext_vector_type(16))) float floatx16;
typedef __attribute__((ext_vector_type(8))) short short8;

// Problem constants
#define BB 16
#define SS 512
#define DD 2048
#define HH_ 16
#define HD 128
#define GG 4
#define MM (BB*SS)          // 8192
#define NQKV 3072           // 2048 q + 512 k + 512 v

__device__ __forceinline__ unsigned short f2bf(float f){
  unsigned u = __builtin_bit_cast(unsigned, f);
  u += 0x7fffu + ((u >> 16) & 1u);            // RNE
  return (unsigned short)(u >> 16);
}
__device__ __forceinline__ float bf2f_lo(unsigned d){
  return __builtin_bit_cast(float, d << 16);
}
__device__ __forceinline__ float bf2f_hi(unsigned d){
  return __builtin_bit_cast(float, d & 0xffff0000u);
}

// NOTE: LDS dest must be WAVE-UNIFORM; HW writes base + lane*16.
__device__ __forceinline__ void async_copy16(const void* g, void* l){
  __builtin_amdgcn_global_load_lds((const __attribute__((address_space(1))) unsigned*)g,
                                   (__attribute__((address_space(3))) unsigned*)l,
                                   16, 0, 0);
}

// ---------------- fused prep: cvt_x | 4x transpose | bias concat ----------------
#define PB_CVT   16384
#define PB_TRQ   (PB_CVT + 4096)
#define PB_TRK   (PB_TRQ + 1024)
#define PB_TRV   (PB_TRK + 1024)
#define PB_TRO   (PB_TRV + 4096)
#define PB_ALL   (PB_TRO + 12)

__global__ __launch_bounds__(256) void prep_kernel(
    const float* __restrict__ x,
    const float* __restrict__ Wq, const float* __restrict__ Wk,
    const float* __restrict__ Wv, const float* __restrict__ Wo,
    const float* __restrict__ bq, const float* __restrict__ bk,
    const float* __restrict__ bv,
    unsigned short* __restrict__ xb, unsigned short* __restrict__ WqkvT,
    unsigned short* __restrict__ WoT, float* __restrict__ bqkv)
{
  __shared__ float tile[32][33];
  const int bid = blockIdx.x, tid = threadIdx.x;

  if (bid < PB_CVT) {                       // ---- x fp32 -> bf16 ----
    const int i = bid * 256 + tid;
    float4 f = ((const float4*)x)[i];
    ushort4 o;
    o.x = f2bf(f.x); o.y = f2bf(f.y); o.z = f2bf(f.z); o.w = f2bf(f.w);
    ((ushort4*)xb)[i] = o;
    return;
  }
  if (bid < PB_TRO) {                       // ---- W transpose+cvt ----
    const float* src; unsigned short* dst; int R, C, b2;
    if (bid < PB_TRQ)      { src = Wq; dst = WqkvT;                          R = 2048; C = 2048; b2 = bid - PB_CVT; }
    else if (bid < PB_TRK) { src = Wk; dst = WqkvT + (size_t)2048 * 2048;    R = 2048; C = 512;  b2 = bid - PB_TRQ; }
    else if (bid < PB_TRV) { src = Wv; dst = WqkvT + (size_t)2560 * 2048;    R = 2048; C = 512;  b2 = bid - PB_TRK; }
    else                   { src = Wo; dst = WoT;                            R = 2048; C = 2048; b2 = bid - PB_TRV; }
    const int nbx = C >> 5;
    const int c0 = (b2 % nbx) * 32, r0 = (b2 / nbx) * 32;
    const int tx = tid & 31, ty = tid >> 5;          // 32 x 8
    #pragma unroll
    for (int j = 0; j < 32; j += 8)
      tile[ty + j][tx] = src[(size_t)(r0 + ty + j) * C + (c0 + tx)];
    __syncthreads();
    #pragma unroll
    for (int j = 0; j < 32; j += 8)
      dst[(size_t)(c0 + ty + j) * R + (r0 + tx)] = f2bf(tile[tx][ty + j]);
    return;
  }
  {                                         // ---- bias concat ----
    const int i = (bid - PB_TRO) * 256 + tid;
    if (i < NQKV)
      bqkv[i] = (i < 2048) ? bq[i] : (i < 2560 ? bk[i - 2048] : bv[i - 2560]);
  }
}

// ---------------- bf16 GEMM (128x128, m97 structure): C = A @ Bt^T + bias ----
// Proven at 117.5us for QKV. 256 threads, BK=64, 32x32x16 MFMA 2x2/wave.
// LDS granule-XOR swizzle via pre-swizzled global source of global_load_lds.
template<bool OUT_BF16>
__global__ __launch_bounds__(256) void gemm_bt_kernel(
    const unsigned short* __restrict__ A,
    const unsigned short* __restrict__ Bt,
    void* __restrict__ Cout,
    const float* __restrict__ bias,
    int M, int N, int K, int ldc)
{
  __shared__ unsigned short sA[128 * 64];   // 16 KB
  __shared__ unsigned short sB[128 * 64];   // 16 KB
  const int tid  = threadIdx.x;
  const int wave = tid >> 6;
  const int lane = tid & 63;
  const int m0 = blockIdx.y * 128;
  const int n0 = blockIdx.x * 128;
  const int wm = (wave >> 1) * 64;
  const int wn = (wave & 1) * 64;

  floatx16 acc[2][2];
  #pragma unroll
  for (int i = 0; i < 2; i++)
    #pragma unroll
    for (int j = 0; j < 2; j++)
      #pragma unroll
      for (int r = 0; r < 16; r++) acc[i][j][r] = 0.f;

  const int sglog = (lane & 7) ^ ((lane >> 3) & 7);
  const unsigned short* gA = A  + (size_t)(m0 + 32 * wave + (lane >> 3)) * K + sglog * 8;
  const unsigned short* gB = Bt + (size_t)(n0 + 32 * wave + (lane >> 3)) * K + sglog * 8;
  unsigned short* lA = &sA[32 * wave * 64];   // wave-uniform; HW adds lane*16B
  unsigned short* lB = &sB[32 * wave * 64];

  for (int k0 = 0; k0 < K; k0 += 64) {
    #pragma unroll
    for (int c = 0; c < 4; ++c) {
      async_copy16(gA + (size_t)c * 8 * K + k0, lA + c * 512);
      async_copy16(gB + (size_t)c * 8 * K + k0, lB + c * 512);
    }
    __syncthreads();

    #pragma unroll
    for (int kh = 0; kh < 4; ++kh) {
      const int slot = (kh * 2 + (lane >> 5)) ^ (lane & 7);
      short8 aF[2], bF[2];
      #pragma unroll
      for (int i = 0; i < 2; ++i)
        aF[i] = *(const short8*)(&sA[(wm + i * 32 + (lane & 31)) * 64 + slot * 8]);
      #pragma unroll
      for (int j = 0; j < 2; ++j)
        bF[j] = *(const short8*)(&sB[(wn + j * 32 + (lane & 31)) * 64 + slot * 8]);
      #pragma unroll
      for (int i = 0; i < 2; ++i)
        #pragma unroll
        for (int j = 0; j < 2; ++j)
          acc[i][j] = __builtin_amdgcn_mfma_f32_32x32x16_bf16(aF[i], bF[j], acc[i][j], 0, 0, 0);
    }
    __syncthreads();
  }

  const int cc = lane & 31;
  const int rb = 4 * (lane >> 5);
  #pragma unroll
  for (int j = 0; j < 2; j++) {
    const int col = n0 + wn + j * 32 + cc;
    const float bval = bias[col];
    #pragma unroll
    for (int i = 0; i < 2; i++) {
      #pragma unroll
      for (int reg = 0; reg < 16; reg++) {
        const int row = m0 + wm + i * 32 + (reg & 3) + 8 * (reg >> 2) + rb;
        const float v = acc[i][j][reg] + bval;
        if (OUT_BF16)
          ((unsigned short*)Cout)[(size_t)row * ldc + col] = f2bf(v);
        else
          ((float*)Cout)[(size_t)row * ldc + col] = v;
      }
    }
  }
}

// ---------------- 256x256 4-phase bf16 GEMM (used for O proj: 256 blocks =
// exactly 1 round at 1 block/CU).
template<bool OUT_BF16>
__global__ __launch_bounds__(512, 2) void gemm256_kernel(
    const unsigned short* __restrict__ A,
    const unsigned short* __restrict__ Bt,
    void* __restrict__ Cout,
    const float* __restrict__ bias,
    int N, int K, int ldc)
{
  __shared__ unsigned short sA[4 * 128 * 64];   // 64 KB: 4 half-slots
  __shared__ unsigned short sB[4 * 128 * 64];   // 64 KB

  const int tid  = threadIdx.x;
  const int wave = tid >> 6, lane = tid & 63;
  const int wm = wave >> 2, wn = wave & 3;      // 2 x 4 wave grid
  const int l15 = lane & 15, l7 = lane & 7, q4 = lane >> 4;

  const int nbn = N >> 8;
  const int cpx = gridDim.x >> 3;
  const int bid = (blockIdx.x & 7) * cpx + (blockIdx.x >> 3);
  const int m0 = (bid / nbn) * 256;
  const int n0 = (bid % nbn) * 256;

  const int rowOff = wave * 8 + (lane >> 3);
  const int glog   = l7 ^ ((lane >> 3) & 7);
  const unsigned short* gA = A  + (size_t)(m0 + rowOff) * K + glog * 8;
  const unsigned short* gB = Bt + (size_t)(n0 + rowOff) * K + glog * 8;

#define STAGE_A(j, tt) do { \
    unsigned short* d_ = &sA[(2 * ((tt) & 1) + (j)) * 8192 + wave * 512]; \
    const unsigned short* s_ = gA + (size_t)((j) * 128) * K + (tt) * 64; \
    async_copy16(s_, d_); \
    async_copy16(s_ + (size_t)64 * K, d_ + 4096); } while (0)
#define STAGE_B(j, tt) do { \
    unsigned short* d_ = &sB[(2 * ((tt) & 1) + (j)) * 8192 + wave * 512]; \
    const unsigned short* s_ = gB + (size_t)((j) * 128) * K + (tt) * 64; \
    async_copy16(s_, d_); \
    async_copy16(s_ + (size_t)64 * K, d_ + 4096); } while (0)
#define FENCE() asm volatile("" ::: "memory")
#define BAR()   do { FENCE(); __builtin_amdgcn_s_barrier(); FENCE(); } while (0)

  STAGE_B(0, 0); STAGE_B(1, 0); STAGE_A(0, 0); STAGE_A(1, 0);
  STAGE_B(0, 1); STAGE_B(1, 1); STAGE_A(0, 1); STAGE_A(1, 1);

  floatx4 acc[8][4];
  #pragma unroll
  for (int i = 0; i < 8; ++i)
    #pragma unroll
    for (int j = 0; j < 4; ++j)
      acc[i][j] = (floatx4){0.f, 0.f, 0.f, 0.f};

  asm volatile("s_waitcnt vmcnt(8)" ::: "memory");
  BAR();

  short8 aF[4][2], bF[4][2];
  const int NT = K >> 6;

  const unsigned short* pA = &sA[l15 * 64];
  const unsigned short* pB = &sB[((wn & 1) * 64 + l15) * 64];
  const int g0 = ((0 + q4) ^ l7) * 8;
  const int g1 = ((4 + q4) ^ l7) * 8;

#define LDA_(fa_, rb_, sa_) do { \
    aF[fa_][0] = *(const short8*)(pA + (sa_) * 8192 + ((rb_) + (fa_) * 16) * 64 + g0); \
    aF[fa_][1] = *(const short8*)(pA + (sa_) * 8192 + ((rb_) + (fa_) * 16) * 64 + g1); } while (0)
#define LDB_(fb_, sb_) do { \
    bF[fb_][0] = *(const short8*)(pB + (sb_) * 8192 + (fb_) * 16 * 64 + g0); \
    bF[fb_][1] = *(const short8*)(pB + (sb_) * 8192 + (fb_) * 16 * 64 + g1); } while (0)
#define MFMA_Q(fa0, fb0) \
    _Pragma("unroll") \
    for (int fa = 0; fa < 4; ++fa) { \
      _Pragma("unroll") \
      for (int fb = 0; fb < 2; ++fb) { \
        acc[(fa0)+fa][(fb0)+fb] = __builtin_amdgcn_mfma_f32_16x16x32_bf16(aF[fa][0], bF[(fb0)+fb][0], acc[(fa0)+fa][(fb0)+fb], 0, 0, 0); \
        acc[(fa0)+fa][(fb0)+fb] = __builtin_amdgcn_mfma_f32_16x16x32_bf16(aF[fa][1], bF[(fb0)+fb][1], acc[(fa0)+fa][(fb0)+fb], 0, 0, 0); \
      } \
    }

  #pragma unroll 1
  for (int t = 0; t < NT; ++t) {
    const int sa = 2 * (t & 1) + wm;
    const int sb = 2 * (t & 1) + (wn >> 1);
    // ---- P0 ----
    LDB_(0, sb); LDB_(1, sb);
    LDA_(0, 0, sa); LDA_(1, 0, sa); LDA_(2, 0, sa); LDA_(3, 0, sa);
    __builtin_amdgcn_s_setprio(1);
    MFMA_Q(0, 0);
    __builtin_amdgcn_s_setprio(0);
    BAR();
    // ---- P1 ----
    LDB_(2, sb); LDB_(3, sb);
    __builtin_amdgcn_s_setprio(1);
    MFMA_Q(0, 2);
    __builtin_amdgcn_s_setprio(0);
    BAR();
    // ---- P2 ----
    LDA_(0, 64, sa); LDA_(1, 64, sa); LDA_(2, 64, sa); LDA_(3, 64, sa);
    if (t + 2 < NT) { STAGE_B(0, t + 2); STAGE_B(1, t + 2); }
    __builtin_amdgcn_s_setprio(1);
    MFMA_Q(4, 0);
    __builtin_amdgcn_s_setprio(0);
    BAR();
    // ---- P3 ----
    if (t + 2 < NT) {
      STAGE_A(0, t + 2); STAGE_A(1, t + 2);
      asm volatile("s_waitcnt vmcnt(8)" ::: "memory");
    } else if (t + 1 < NT) {
      asm volatile("s_waitcnt vmcnt(0)" ::: "memory");
    }
    __builtin_amdgcn_s_setprio(1);
    MFMA_Q(4, 2);
    __builtin_amdgcn_s_setprio(0);
    BAR();
  }
#undef STAGE_A
#undef STAGE_B
#undef LDA_
#undef LDB_
#undef MFMA_Q
#undef FENCE
#undef BAR

  const int r4 = q4 * 4;
  #pragma unroll
  for (int fb = 0; fb < 4; ++fb) {
    const int col = n0 + wn * 64 + fb * 16 + l15;
    const float bval = bias[col];
    #pragma unroll
    for (int fa = 0; fa < 8; ++fa) {
      const size_t rowb = (size_t)(m0 + wm * 128 + fa * 16 + r4);
      #pragma unroll
      for (int r = 0; r < 4; ++r) {
        const float v = acc[fa][fb][r] + bval;
        if (OUT_BF16)
          ((unsigned short*)Cout)[(rowb + r) * ldc + col] = f2bf(v);
        else
          ((float*)Cout)[(rowb + r) * ldc + col] = v;
      }
    }
  }
}

// ---------------- fused RMSNorm+RoPE (q,k) | V transpose ----------------
__global__ __launch_bounds__(256) void norm_vtr_kernel(
    unsigned short* __restrict__ qkv,
    const float* __restrict__ qs, const float* __restrict__ ks,
    unsigned short* __restrict__ vt)
{
  __shared__ unsigned short tileV[32][34];
  const int bid = blockIdx.x, tid = threadIdx.x;

  if (bid < 40960) {
    const int wave = tid >> 6, lane = tid & 63;
    const int gw  = bid * 4 + wave;
    const int row = gw / 20;
    const int hh  = gw % 20;          // 0..15 q heads, 16..19 k heads
    const bool isq = hh < 16;

    unsigned* p = (unsigned*)(qkv + (size_t)row * NQKV + hh * 128) + lane;
    unsigned d = *p;
    float x1 = bf2f_lo(d), x2 = bf2f_hi(d);

    float ss = x1 * x1 + x2 * x2;
    #pragma unroll
    for (int off = 32; off; off >>= 1) ss += __shfl_xor(ss, off, 64);
    const float r = rsqrtf(ss * (1.f / 128.f) + 1e-6f);

    const float2 sc = ((const float2*)(isq ? qs : ks))[lane];
    float n1 = x1 * r * sc.x;
    float n2 = x2 * r * sc.y;

    const float t = (float)(row & (SS - 1));
    const float freq = __expf((float)lane * (-2.f / 128.f) * 9.21034037197618f);
    float sn, cs;
    __sincosf(t * freq, &sn, &cs);
    float o1 = n1 * cs - n2 * sn;
    float o2 = n1 * sn + n2 * cs;
    if (isq) { o1 *= (1.f / 128.f); o2 *= (1.f / 128.f); }

    *p = (unsigned)f2bf(o1) | ((unsigned)f2bf(o2) << 16);
    return;
  }
  {
    const int b2 = bid - 40960;
    const int hd0 = (b2 & 3) * 32, t0 = ((b2 >> 2) & 15) * 32, bg = b2 >> 6;
    const int tx = tid & 31, ty = tid >> 5;
    const int b = bg >> 2, g = bg & 3;
    const unsigned short* src = qkv + (size_t)b * SS * NQKV + 2560 + g * HD;
    #pragma unroll
    for (int j = 0; j < 32; j += 8)
      tileV[ty + j][tx] = src[(size_t)(t0 + ty + j) * NQKV + hd0 + tx];
    __syncthreads();
    unsigned short* dst = vt + (size_t)bg * HD * SS;
    #pragma unroll
    for (int j = 0; j < 32; j += 8)
      dst[(size_t)(hd0 + ty + j) * SS + t0 + tx] = tileV[tx][ty + j];
  }
}

// ---------------- MFMA flash attention, 8-wave / 128 q-rows per block -------
// R2 single-buffer counters: MfmaUtil 1.5%, all pipes idle -> latency-bound.
// R3 dbuf helped some; this version doubles TLP and halves staging/MFMA:
//  - 8 waves share one K/V tile (staging bytes per MFMA halved; 4 copies/thr)
//  - LDS = 32+32+16 = 80 KB -> 2 blocks/CU -> 16 waves/CU = 4 waves/SIMD
//  - grid 1024; qb dispatch pairing {3,0,2,1} balances causal load per round
//  - ONE __syncthreads per tile; stage(kt+1 -> buf^1) right after it
// Waves 0-3 compute a fully-masked tile at kt=2qb+1 (~10% waste) — the cost
// of sharing one K/V stage across 128 q-rows.
__global__ __launch_bounds__(512, 4) void fattn_kernel(
    const unsigned short* __restrict__ qkv,
    const unsigned short* __restrict__ vtb,
    unsigned short* __restrict__ aout)
{
  __shared__ unsigned short sK[2][64 * 128];  // 32 KB
  __shared__ unsigned short sV[2][128 * 64];  // 32 KB
  __shared__ unsigned short sP[8][16 * 64];   // 16 KB  (80 KB total)

  const int lane = threadIdx.x & 63, wave = threadIdx.x >> 6;
  const int quad = lane >> 4, col = lane & 15;
  const int idx = blockIdx.x;
  const int qb = (0x1203 >> ((idx >> 8) * 4)) & 0xF;   // {3,0,2,1} pairing
  const int bh = idx & 255;
  const int b = bh >> 4, h = bh & 15, g = h >> 2;

  const int qrow = qb * 128 + wave * 16 + col;
  const unsigned short* qg = qkv + ((size_t)(b * SS + qrow)) * NQKV + h * HD + quad * 8;
  short8 qf[4];
  #pragma unroll
  for (int c = 0; c < 4; ++c) qf[c] = *(const short8*)(qg + c * 32);

  const unsigned short* kg = qkv + (size_t)b * SS * NQKV + 2048 + g * HD;
  const unsigned short* vg = vtb + ((size_t)(b * GG + g)) * HD * SS;

  floatx4 acc_o[8];
  #pragma unroll
  for (int i = 0; i < 8; ++i) acc_o[i] = (floatx4){0.f, 0.f, 0.f, 0.f};
  float m[4] = {-INFINITY, -INFINITY, -INFINITY, -INFINITY};
  float l[4] = {0.f, 0.f, 0.f, 0.f};

#define STAGE_KV(kt_, bf_) do { \
    const int t0_ = (kt_) * 64; \
    _Pragma("unroll") \
    for (int c = 0; c < 2; ++c) { \
      const int ci = c * 8 + wave; \
      { const int r_  = ci * 4 + (lane >> 4); \
        const int gl_ = (lane & 15) ^ (r_ & 15); \
        async_copy16(kg + (size_t)(t0_ + r_) * NQKV + gl_ * 8, &sK[bf_][ci * 512]); } \
      { const int r_  = ci * 8 + (lane >> 3); \
        const int gl_ = (lane & 7) ^ (r_ & 7); \
        async_copy16(vg + (size_t)r_ * SS + t0_ + gl_ * 8, &sV[bf_][ci * 512]); } \
    } } while (0)

  const int nkt = 2 * qb + 2;
  STAGE_KV(0, 0);

  for (int kt = 0; kt < nkt; ++kt) {
    const int buf = kt & 1;
    __syncthreads();                          // retires tile-kt copies; releases buf^1
    if (kt + 1 < nkt) STAGE_KV(kt + 1, buf ^ 1);

    floatx4 sc[4];
    #pragma unroll
    for (int s = 0; s < 4; ++s) sc[s] = (floatx4){0.f, 0.f, 0.f, 0.f};
    __builtin_amdgcn_s_setprio(1);
    #pragma unroll
    for (int s = 0; s < 4; ++s) {
      const int trow = s * 16 + col;
      #pragma unroll
      for (int c = 0; c < 4; ++c) {
        const int p = (c * 4 + quad) ^ (trow & 15);
        const short8 kf = *(const short8*)(&sK[buf][trow * 128 + p * 8]);
        sc[s] = __builtin_amdgcn_mfma_f32_16x16x32_bf16(qf[c], kf, sc[s], 0, 0, 0);
      }
    }
    __builtin_amdgcn_s_setprio(0);

    if (kt >= 2 * qb) {                       // diagonal (and beyond) tiles
      #pragma unroll
      for (int s = 0; s < 4; ++s)
        #pragma unroll
        for (int r = 0; r < 4; ++r)
          if (kt * 64 + s * 16 + col > qb * 128 + wave * 16 + quad * 4 + r)
            sc[s][r] = -1e30f;
    }

    float mx[4], alpha[4], lsum[4];
    #pragma unroll
    for (int r = 0; r < 4; ++r) {
      mx[r] = fmaxf(fmaxf(sc[0][r], sc[1][r]), fmaxf(sc[2][r], sc[3][r]));
      #pragma unroll
      for (int off = 8; off; off >>= 1) mx[r] = fmaxf(mx[r], __shfl_xor(mx[r], off, 16));
      mx[r] = fmaxf(mx[r], m[r]);
      alpha[r] = __expf(m[r] - mx[r]);
      m[r] = mx[r];
      lsum[r] = 0.f;
    }
    // P write: row=quad*4+r, col_t=s*16+col; granule g=s*2+(col>>3), slot=g^(row&7)
    #pragma unroll
    for (int s = 0; s < 4; ++s)
      #pragma unroll
      for (int r = 0; r < 4; ++r) {
        const float p = __expf(sc[s][r] - m[r]);
        lsum[r] += p;
        const int row = quad * 4 + r;
        const int slot = (s * 2 + (col >> 3)) ^ (row & 7);
        sP[wave][row * 64 + slot * 8 + (col & 7)] = f2bf(p);
      }
    #pragma unroll
    for (int r = 0; r < 4; ++r) {
      #pragma unroll
      for (int off = 8; off; off >>= 1) lsum[r] += __shfl_xor(lsum[r], off, 16);
      l[r] = l[r] * alpha[r] + lsum[r];
    }
    #pragma unroll
    for (int n = 0; n < 8; ++n)
      #pragma unroll
      for (int r = 0; r < 4; ++r) acc_o[n][r] *= alpha[r];

    // P read (A-frag): m=col, k=kc*32+quad*8+j -> granule kc*4+quad, slot ^(m&7)
    // (sP write->read dep is wave-private; compiler inserts the lgkmcnt)
    short8 pf[2];
    #pragma unroll
    for (int kc = 0; kc < 2; ++kc)
      pf[kc] = *(const short8*)(&sP[wave][col * 64 + ((kc * 4 + quad) ^ (col & 7)) * 8]);
    __builtin_amdgcn_s_setprio(1);
    #pragma unroll
    for (int n = 0; n < 8; ++n) {
      const int hdrow = n * 16 + col;
      #pragma unroll
      for (int kc = 0; kc < 2; ++kc) {
        const int p = (kc * 4 + quad) ^ (hdrow & 7);
        const short8 vf = *(const short8*)(&sV[buf][hdrow * 64 + p * 8]);
        acc_o[n] = __builtin_amdgcn_mfma_f32_16x16x32_bf16(pf[kc], vf, acc_o[n], 0, 0, 0);
      }
    }
    __builtin_amdgcn_s_setprio(0);
  }
#undef STAGE_KV

  float inv[4];
  #pragma unroll
  for (int r = 0; r < 4; ++r) inv[r] = 1.f / l[r];
  unsigned short* ob = aout + ((size_t)(b * SS + qb * 128 + wave * 16)) * DD + h * HD;
  #pragma unroll
  for (int n = 0; n < 8; ++n)
    #pragma unroll
    for (int r = 0; r < 4; ++r)
      ob[(size_t)(quad * 4 + r) * DD + n * 16 + col] = f2bf(acc_o[n][r] * inv[r]);
}

extern "C" void kernel_launch(void* const* d_in, const int* in_sizes, int n_in,
                              void* d_out, int out_size, void* d_ws, size_t ws_size,
                              hipStream_t stream) {
  const float* x   = (const float*)d_in[0];
  const float* Wq  = (const float*)d_in[1];
  const float* bq  = (const float*)d_in[2];
  const float* Wk  = (const float*)d_in[3];
  const float* bk  = (const float*)d_in[4];
  const float* Wv  = (const float*)d_in[5];
  const float* bv  = (const float*)d_in[6];
  const float* Wo  = (const float*)d_in[7];
  const float* bo  = (const float*)d_in[8];
  const float* qns = (const float*)d_in[9];
  const float* kns = (const float*)d_in[10];

  char* ws = (char*)d_ws;
  unsigned short* xb    = (unsigned short*)(ws);                 // 8192x2048 bf16 (dead after QKV gemm)
  unsigned short* vtb   = (unsigned short*)(ws);                 // 16x4x128x512 bf16 (reuses xb)
  unsigned short* WqkvT = (unsigned short*)(ws + 33554432);      // 3072x2048 bf16
  unsigned short* WoT   = (unsigned short*)(ws + 46137344);      // 2048x2048 bf16
  float*          bqkv  = (float*)         (ws + 54525952);      // 3072 f32
  unsigned short* qkv   = (unsigned short*)(ws + 54538240);      // 8192x3072 bf16
  unsigned short* aout  = (unsigned short*)(ws + 104869888);     // 8192x2048 bf16

  prep_kernel<<<PB_ALL, 256, 0, stream>>>(x, Wq, Wk, Wv, Wo, bq, bk, bv,
                                          xb, WqkvT, WoT, bqkv);
  // QKV: 128^2 tiles (proven 117.5us): grid (N/128, M/128) = (24, 64)
  gemm_bt_kernel<true><<<dim3(24, 64), 256, 0, stream>>>(xb, WqkvT, qkv, bqkv,
                                                         MM, NQKV, DD, NQKV);
  norm_vtr_kernel<<<45056, 256, 0, stream>>>(qkv, qns, kns, vtb);
  // fattn: 8 waves / 128 q-rows per block; 16*16*4 = 1024 blocks
  fattn_kernel<<<1024, 512, 0, stream>>>(qkv, vtb, aout);
  // O: 256^2 4-phase, 256 blocks = exactly 1 round at 1 block/CU
  gemm256_kernel<false><<<256, 512, 0, stream>>>(aout, WoT, d_out, bo,
                                                 DD, DD, DD);
  (void)in_sizes; (void)n_in; (void)out_size; (void)ws_size;
}